// Round 3
// baseline (483.320 us; speedup 1.0000x reference)
//
#include <hip/hip_runtime.h>

// ---------------------------------------------------------------------------
// T5GNNAdapt: LN -> RGCN scatter-mean (2 relations) -> [h0|h1|x] @ [W0;W1;root]
//             + bias -> relu -> @wo -> + residual
// Shapes: B=8,S=1024,D=1024,F=4096,E=262144,N=B*S=8192, K_cat=3072
// R7: gemm1 -> 256^2 8-phase counted-vmcnt template: 190us, MfmaUtil 47.7%.
// R8: gemm2 -> same template (256x128, 2 phases/K-tile, VM2): total 501->474.
// R9: (a) aggregate rewritten wave-per-bucket: no LDS, no syncs, no cross-
//     wave reduce; edge ids broadcast via __shfl; 4-deep load unroll.
//     (b) gemm1: A-frag prefetch one phase ahead (two register banks) —
//     phases 1-3 consume frags issued during the previous phase's MFMA, so
//     their lgkmcnt(0) is free. Barriers/vmcnt placement UNCHANGED.
// ---------------------------------------------------------------------------

typedef unsigned short u16;
typedef unsigned int   u32;
typedef __attribute__((ext_vector_type(8))) short bf16x8;
typedef __attribute__((ext_vector_type(4))) float f32x4;
typedef __attribute__((ext_vector_type(2))) float f32x2;

#define E_NUM  262144
#define NNODE  8192
#define NBKT   (2 * NNODE)      // 16384 (rel,dst) buckets
#define DDIM   1024
#define FDIM   4096
#define KCAT   3072
#define LN_EPS 1e-6f

struct alignas(8) u16x4 { u16 x, y, z, w; };

__device__ __forceinline__ u16 f2bf(float f) {
  u32 u = __float_as_uint(f);
  u32 r = u + 0x7fffu + ((u >> 16) & 1u);   // RNE
  return (u16)(r >> 16);
}
__device__ __forceinline__ float bf2f(u16 h) {
  return __uint_as_float(((u32)h) << 16);
}

// ---- fp8 e4m3fn (OCP) encode/decode; HW cvt when available ---------------
__device__ __forceinline__ u32 enc_fp8_1(float f) {
  u32 u = __float_as_uint(f);
  u32 s = u >> 31;
  u32 mag = u & 0x7fffffffu;
  mag = mag + 0x7ffffu + ((mag >> 20) & 1u);          // RNE to 3 mant bits
  if (mag > 0x43e00000u) mag = 0x43e00000u;           // clamp to 448
  u32 e = mag >> 23;
  return (e <= 120u) ? 0u
                     : ((s << 7) | ((e - 120u) << 3) | ((mag >> 20) & 7u));
}

__device__ __forceinline__ u32 pack4_fp8(float a, float b, float c, float d) {
#if __has_builtin(__builtin_amdgcn_cvt_pk_fp8_f32)
  int v = 0;
  v = __builtin_amdgcn_cvt_pk_fp8_f32(a, b, v, false);  // bytes 0,1
  v = __builtin_amdgcn_cvt_pk_fp8_f32(c, d, v, true);   // bytes 2,3
  return (u32)v;
#else
  return enc_fp8_1(a) | (enc_fp8_1(b) << 8) | (enc_fp8_1(c) << 16) |
         (enc_fp8_1(d) << 24);
#endif
}

__device__ __forceinline__ float dec_fp8_1(u32 b) {
  u32 e = (b >> 3) & 15u;
  u32 f = ((b & 0x80u) << 24) | ((e + 120u) << 23) | ((b & 7u) << 20);
  return e ? __uint_as_float(f) : 0.0f;
}

__device__ __forceinline__ void acc4_fp8(float* a, u32 q) {
#if __has_builtin(__builtin_amdgcn_cvt_pk_f32_fp8)
  f32x2 p0 = __builtin_amdgcn_cvt_pk_f32_fp8((int)q, false);
  f32x2 p1 = __builtin_amdgcn_cvt_pk_f32_fp8((int)q, true);
  a[0] += p0.x; a[1] += p0.y; a[2] += p1.x; a[3] += p1.y;
#else
  a[0] += dec_fp8_1(q);       a[1] += dec_fp8_1(q >> 8);
  a[2] += dec_fp8_1(q >> 16); a[3] += dec_fp8_1(q >> 24);
#endif
}

__device__ __forceinline__ void acc16_fp8(float* a, uint4 x) {
  acc4_fp8(a + 0,  x.x); acc4_fp8(a + 4,  x.y);
  acc4_fp8(a + 8,  x.z); acc4_fp8(a + 12, x.w);
}

// 16-byte global -> LDS async copy (wave-uniform LDS base + lane*16 layout)
#define GLD16(gp, lp)                                              \
  __builtin_amdgcn_global_load_lds(                                \
      (__attribute__((address_space(1))) u32*)(gp),                \
      (__attribute__((address_space(3))) u32*)(lp), 16, 0, 0)

// ---------------------------------------------------------------------------
// K1: LayerNorm (one-pass). Writes bf16 x into hcat[:, 2048:3072] AND fp8
// copy into dense xq[8192x1024] (aggregation gather input).
// ---------------------------------------------------------------------------
__global__ void ln_kernel(const float* __restrict__ hs,
                          const float* __restrict__ gamma,
                          const float* __restrict__ beta,
                          u16* __restrict__ hcat,
                          u32* __restrict__ xq) {
  const int row = blockIdx.x;
  const int tid = threadIdx.x;
  const float4 v = ((const float4*)(hs + (size_t)row * DDIM))[tid];

  __shared__ float r1[256], r2[256];
  r1[tid] = v.x + v.y + v.z + v.w;
  r2[tid] = v.x * v.x + v.y * v.y + v.z * v.z + v.w * v.w;
  __syncthreads();
  for (int st = 128; st > 0; st >>= 1) {
    if (tid < st) { r1[tid] += r1[tid + st]; r2[tid] += r2[tid + st]; }
    __syncthreads();
  }
  const float mean = r1[0] * (1.0f / DDIM);
  const float var  = r2[0] * (1.0f / DDIM) - mean * mean;
  const float rs   = rsqrtf(var + LN_EPS);

  const int base = tid * 4;
  const float4 g = *(const float4*)(gamma + base);
  const float4 b = *(const float4*)(beta + base);
  const float o0 = (v.x - mean) * rs * g.x + b.x;
  const float o1 = (v.y - mean) * rs * g.y + b.y;
  const float o2 = (v.z - mean) * rs * g.z + b.z;
  const float o3 = (v.w - mean) * rs * g.w + b.w;
  u16x4 o;
  o.x = f2bf(o0); o.y = f2bf(o1); o.z = f2bf(o2); o.w = f2bf(o3);
  *(u16x4*)(hcat + (size_t)row * KCAT + 2048 + base) = o;
  xq[row * 256 + tid] = pack4_fp8(o0, o1, o2, o3);
}

// ---------------------------------------------------------------------------
// K2: f32 [K,N] -> bf16 [N,K] transpose (stitches two sources along K).
// ---------------------------------------------------------------------------
__global__ void cvt_transpose(const float* __restrict__ srcA,
                              const float* __restrict__ srcB,
                              int splitK, int K, int N,
                              u16* __restrict__ dst) {
  __shared__ float tile[32][33];
  const int n0 = blockIdx.x * 32, k0 = blockIdx.y * 32;
  const int tx = threadIdx.x, ty = threadIdx.y;
  for (int i = ty; i < 32; i += 8) {
    const int k = k0 + i;
    const float v = (k < splitK) ? srcA[(size_t)k * N + n0 + tx]
                                 : srcB[(size_t)(k - splitK) * N + n0 + tx];
    tile[i][tx] = v;
  }
  __syncthreads();
  for (int i = ty; i < 32; i += 8) {
    dst[(size_t)(n0 + i) * K + k0 + tx] = f2bf(tile[tx][i]);
  }
}

// ---------------------------------------------------------------------------
// K3a: count edges per (rel,dst) bucket.
// ---------------------------------------------------------------------------
__global__ void count_kernel(const int* __restrict__ edge_index,
                             const int* __restrict__ edge_type,
                             int* __restrict__ cnt) {
  const int e = blockIdx.x * 256 + threadIdx.x;
  const int d = edge_index[E_NUM + e];
  const int r = edge_type[e];
  atomicAdd(&cnt[r * NNODE + d], 1);
}

// ---------------------------------------------------------------------------
// K3b: exclusive prefix sum over 16384 counts (single block, 1024 thr).
// ---------------------------------------------------------------------------
__global__ __launch_bounds__(1024) void scan_kernel(const int* __restrict__ cnt,
                                                    int* __restrict__ off,
                                                    int* __restrict__ cursor) {
  __shared__ int partial[1024];
  const int tid  = threadIdx.x;
  const int base = tid * 16;
  int local[16];
  int s = 0;
#pragma unroll
  for (int i = 0; i < 16; ++i) { local[i] = s; s += cnt[base + i]; }
  partial[tid] = s;
  __syncthreads();
  for (int st = 1; st < 1024; st <<= 1) {
    const int v = (tid >= st) ? partial[tid - st] : 0;
    __syncthreads();
    partial[tid] += v;
    __syncthreads();
  }
  const int pre = (tid == 0) ? 0 : partial[tid - 1];
#pragma unroll
  for (int i = 0; i < 16; ++i) {
    const int o = pre + local[i];
    off[base + i]    = o;
    cursor[base + i] = o;
  }
}

// ---------------------------------------------------------------------------
// K3c: scatter edge SOURCE ids into buckets (4B per edge, not row data).
// ---------------------------------------------------------------------------
__global__ void fill_kernel(const int* __restrict__ edge_index,
                            const int* __restrict__ edge_type,
                            int* __restrict__ cursor,
                            int* __restrict__ bucket_src) {
  const int e = blockIdx.x * 256 + threadIdx.x;
  const int s = edge_index[e];
  const int d = edge_index[E_NUM + e];
  const int r = edge_type[e];
  const int pos = atomicAdd(&cursor[r * NNODE + d], 1);
  bucket_src[pos] = s;
}

// ---------------------------------------------------------------------------
// K4 (R9): wave-per-bucket aggregation. One 64-lane wave owns one (rel,node)
// bucket; lane covers 16 cols (dwordx4 of fp8). Edge ids held in a register
// and broadcast via __shfl — no LDS, no __syncthreads, no cross-wave reduce.
// 4-deep manual unroll keeps 4 gather loads in flight. 4 buckets/block.
// ---------------------------------------------------------------------------
__global__ __launch_bounds__(256) void aggregate_kernel(
    const int* __restrict__ cnt, const int* __restrict__ off,
    const int* __restrict__ bucket_src, const u32* __restrict__ xq,
    u16* __restrict__ hcat) {
  const int b    = blockIdx.x * 4 + (threadIdx.x >> 6);  // bucket id
  const int lane = threadIdx.x & 63;
  const int r    = b >> 13;
  const int node = b & (NNODE - 1);
  const int n     = cnt[b];
  const int start = off[b];

  float a[16] = {};

  for (int j0 = 0; j0 < n; j0 += 64) {
    const int m = min(n - j0, 64);
    const int myid = (lane < m) ? bucket_src[start + j0 + lane] : 0;
    int j = 0;
    for (; j + 3 < m; j += 4) {
      const int s0 = __shfl(myid, j,     64);
      const int s1 = __shfl(myid, j + 1, 64);
      const int s2 = __shfl(myid, j + 2, 64);
      const int s3 = __shfl(myid, j + 3, 64);
      const uint4 x0 = *(const uint4*)(xq + s0 * 256 + lane * 4);
      const uint4 x1 = *(const uint4*)(xq + s1 * 256 + lane * 4);
      const uint4 x2 = *(const uint4*)(xq + s2 * 256 + lane * 4);
      const uint4 x3 = *(const uint4*)(xq + s3 * 256 + lane * 4);
      acc16_fp8(a, x0); acc16_fp8(a, x1);
      acc16_fp8(a, x2); acc16_fp8(a, x3);
    }
    for (; j < m; ++j) {
      const int s0 = __shfl(myid, j, 64);
      const uint4 x0 = *(const uint4*)(xq + s0 * 256 + lane * 4);
      acc16_fp8(a, x0);
    }
  }

  const float inv = 1.0f / fmaxf((float)n, 1.0f);
  uint4 o0, o1;
  o0.x = (u32)f2bf(a[0] * inv)  | ((u32)f2bf(a[1] * inv)  << 16);
  o0.y = (u32)f2bf(a[2] * inv)  | ((u32)f2bf(a[3] * inv)  << 16);
  o0.z = (u32)f2bf(a[4] * inv)  | ((u32)f2bf(a[5] * inv)  << 16);
  o0.w = (u32)f2bf(a[6] * inv)  | ((u32)f2bf(a[7] * inv)  << 16);
  o1.x = (u32)f2bf(a[8] * inv)  | ((u32)f2bf(a[9] * inv)  << 16);
  o1.y = (u32)f2bf(a[10] * inv) | ((u32)f2bf(a[11] * inv) << 16);
  o1.z = (u32)f2bf(a[12] * inv) | ((u32)f2bf(a[13] * inv) << 16);
  o1.w = (u32)f2bf(a[14] * inv) | ((u32)f2bf(a[15] * inv) << 16);
  u16* dp = hcat + (size_t)node * KCAT + (size_t)r * DDIM + lane * 16;
  *(uint4*)(dp)     = o0;
  *(uint4*)(dp + 8) = o1;
}

// ---------------------------------------------------------------------------
// Shared 8-phase GEMM machinery (expanded in gemm kernels; names resolve to
// kernel-local variables at expansion site).
// ---------------------------------------------------------------------------

#define MF16(a, b, c) __builtin_amdgcn_mfma_f32_16x16x32_bf16(a, b, c, 0, 0, 0)

#define STAGE_A(t, p, b)                                                   \
  { GLD16(gA0 + (size_t)(t) * 64 + (size_t)(p) * KP,                       \
          &sA[b][(p) * 8192 + lofs0]);                                     \
    GLD16(gA1 + (size_t)(t) * 64 + (size_t)(p) * KP,                       \
          &sA[b][(p) * 8192 + lofs1]); }

#define STAGE_B(t, p, b)                                                   \
  { GLD16(gB0 + (size_t)(t) * 64 + (size_t)(p) * KP,                       \
          &sB[b][(p) * 8192 + lofs0]);                                     \
    GLD16(gB1 + (size_t)(t) * 64 + (size_t)(p) * KP,                       \
          &sB[b][(p) * 8192 + lofs1]); }

#define BVLOAD(b)                                                          \
  { const bf16x8* pB_ = (const bf16x8*)sB[b];                              \
    bv[0][0] = pB_[brow80 + sega0]; bv[0][1] = pB_[brow80 + sega1];        \
    bv[1][0] = pB_[brow81 + sega0]; bv[1][1] = pB_[brow81 + sega1];        \
    bv[2][0] = pB_[brow82 + sega0]; bv[2][1] = pB_[brow82 + sega1];        \
    bv[3][0] = pB_[brow83 + sega0]; bv[3][1] = pB_[brow83 + sega1]; }

#define NOWAIT ((void)0)
#define NOSTAGE ((void)0)
#define NOOP ((void)0)
#define VM4 asm volatile("s_waitcnt vmcnt(4)" ::: "memory")
#define VM2 asm volatile("s_waitcnt vmcnt(2)" ::: "memory")
#define VM0 asm volatile("s_waitcnt vmcnt(0)" ::: "memory")

// A-fragment register-bank read for phase Q from buffer BUFI.
#define AREAD(BANK, Q, BUFI)                                               \
  { const bf16x8* pA_ = (const bf16x8*)sA[BUFI];                           \
    af##BANK##0 = pA_[arow8[2 * (Q)] + sega0];                             \
    af##BANK##1 = pA_[arow8[2 * (Q)] + sega1];                             \
    af##BANK##2 = pA_[arow8[2 * (Q) + 1] + sega0];                         \
    af##BANK##3 = pA_[arow8[2 * (Q) + 1] + sega1]; }

#define AMFMA(BANK, Q)                                                     \
    _Pragma("unroll")                                                      \
    for (int ni = 0; ni < 4; ++ni) {                                       \
      acc[2 * (Q)][ni]     = MF16(af##BANK##0, bv[ni][0], acc[2 * (Q)][ni]);\
      acc[2 * (Q)][ni]     = MF16(af##BANK##1, bv[ni][1], acc[2 * (Q)][ni]);\
      acc[2 * (Q) + 1][ni] = MF16(af##BANK##2, bv[ni][0], acc[2 * (Q) + 1][ni]);\
      acc[2 * (Q) + 1][ni] = MF16(af##BANK##3, bv[ni][1], acc[2 * (Q) + 1][ni]);\
    }

// R9 phase: OWN = reads that must complete THIS phase (phase-0 only);
// PRE = next phase's A-frag reads, issued after the wait so they complete
// under this phase's MFMA + barrier. sched_barrier(0) pins PRE before MFMA.
#define PHX(Q, BANK, OWN, PRE, STAGE, ENDW)                                \
  { OWN;                                                                   \
    STAGE;                                                                 \
    __builtin_amdgcn_s_barrier();                                          \
    asm volatile("s_waitcnt lgkmcnt(0)" ::: "memory");                     \
    PRE;                                                                   \
    __builtin_amdgcn_sched_barrier(0);                                     \
    __builtin_amdgcn_s_setprio(1);                                         \
    AMFMA(BANK, Q)                                                         \
    __builtin_amdgcn_s_setprio(0);                                         \
    ENDW;                                                                  \
    __builtin_amdgcn_s_barrier(); }

// Legacy phase (gemm2): reads its own A-frags at phase top.
#define PHASE(Q, BUFI, STAGE, ENDW)                                        \
  { const bf16x8* pA_ = (const bf16x8*)sA[BUFI];                           \
    bf16x8 a00 = pA_[arow8[2 * (Q)] + sega0];                              \
    bf16x8 a01 = pA_[arow8[2 * (Q)] + sega1];                              \
    bf16x8 a10 = pA_[arow8[2 * (Q) + 1] + sega0];                          \
    bf16x8 a11 = pA_[arow8[2 * (Q) + 1] + sega1];                          \
    STAGE;                                                                 \
    __builtin_amdgcn_s_barrier();                                          \
    asm volatile("s_waitcnt lgkmcnt(0)" ::: "memory");                     \
    __builtin_amdgcn_s_setprio(1);                                         \
    _Pragma("unroll")                                                      \
    for (int ni = 0; ni < 4; ++ni) {                                       \
      acc[2 * (Q)][ni]     = MF16(a00, bv[ni][0], acc[2 * (Q)][ni]);       \
      acc[2 * (Q)][ni]     = MF16(a01, bv[ni][1], acc[2 * (Q)][ni]);       \
      acc[2 * (Q) + 1][ni] = MF16(a10, bv[ni][0], acc[2 * (Q) + 1][ni]);   \
      acc[2 * (Q) + 1][ni] = MF16(a11, bv[ni][1], acc[2 * (Q) + 1][ni]);   \
    }                                                                      \
    __builtin_amdgcn_s_setprio(0);                                         \
    ENDW;                                                                  \
    __builtin_amdgcn_s_barrier(); }

// ---------------------------------------------------------------------------
// GEMM1: out1[8192x4096] = bf16(relu(hcat[8192x3072] @ WcatT^T + bias))
// 256x256 tile, BK=64, 512 thr / 8 waves (2Mx4N), 128 KiB dbuf LDS,
// 8-phase counted-vmcnt schedule; vmcnt(4) only at phases 4/8.
// R9: A-frag prefetch one phase ahead (banks af0*/af1*); phases 1-3 have a
// free lgkmcnt(0). Prefetches stay within the current buffer — the phase-3
// cross-buffer boundary (needs VM4) is NOT prefetched. Barriers unchanged.
// ---------------------------------------------------------------------------
__global__ __launch_bounds__(512) void gemm1_kernel(
    const u16* __restrict__ A, const u16* __restrict__ Bt,
    const float* __restrict__ bias, u16* __restrict__ obf) {
  const int K = KCAT, N = FDIM;
  const int NT = K / 64;                    // 48 K-tiles
  const size_t KP = (size_t)128 * K;        // piece-1 global row offset
  __shared__ __align__(16) u16 sA[2][16384];  // 64 KB (2 bufs x 256x64 bf16)
  __shared__ __align__(16) u16 sB[2][16384];  // 64 KB

  const int tid  = threadIdx.x;
  const int lane = tid & 63;
  const int wave = tid >> 6;
  const int wr = wave >> 2, wc = wave & 3;    // 2 x 4 wave grid
  const int lr = lane & 15, quad = lane >> 4;

  const int bid = blockIdx.x;
  const int swz = (bid & 7) * 64 + (bid >> 3);
  const int bm = (swz >> 4) * 256;
  const int bn = (swz & 15) * 256;

  int lofs0, lofs1;
  const u16 *gA0, *gA1, *gB0, *gB1;
  {
    const int s0 = tid,       r0 = s0 >> 3, g0 = (s0 & 7) ^ (r0 & 7);
    const int s1 = tid + 512, r1 = s1 >> 3, g1 = (s1 & 7) ^ (r1 & 7);
    gA0 = A  + (size_t)(bm + r0) * K + g0 * 8;
    gA1 = A  + (size_t)(bm + r1) * K + g1 * 8;
    gB0 = Bt + (size_t)(bn + r0) * K + g0 * 8;
    gB1 = Bt + (size_t)(bn + r1) * K + g1 * 8;
    lofs0 = s0 * 8; lofs1 = s1 * 8;
  }

  int arow8[8];
#pragma unroll
  for (int mi = 0; mi < 8; ++mi) arow8[mi] = (wr * 128 + mi * 16 + lr) * 8;
  const int brow80 = (wc * 64 +  0 + lr) * 8;
  const int brow81 = (wc * 64 + 16 + lr) * 8;
  const int brow82 = (wc * 64 + 32 + lr) * 8;
  const int brow83 = (wc * 64 + 48 + lr) * 8;
  const int sega0 = quad ^ (lr & 7);
  const int sega1 = (4 + quad) ^ (lr & 7);

  f32x4 acc[8][4] = {};
  bf16x8 bv[4][2];
  bf16x8 af00, af01, af02, af03;   // A-frag bank 0
  bf16x8 af10, af11, af12, af13;   // A-frag bank 1

  STAGE_B(0, 0, 0) STAGE_B(0, 1, 0)
  STAGE_A(0, 0, 0) STAGE_A(0, 1, 0)
  STAGE_B(1, 0, 1) STAGE_B(1, 1, 1)
  asm volatile("s_waitcnt vmcnt(4)" ::: "memory");
  __builtin_amdgcn_s_barrier();

  for (int tt = 0; tt < NT - 2; tt += 2) {
    // tile tt (buf0)
    PHX(0, 0, AREAD(0, 0, 0); BVLOAD(0), AREAD(1, 1, 0), STAGE_A(tt + 1, 0, 1), NOWAIT)
    PHX(1, 1, NOOP,                      AREAD(0, 2, 0), STAGE_A(tt + 1, 1, 1), NOWAIT)
    PHX(2, 0, NOOP,                      AREAD(1, 3, 0), STAGE_B(tt + 2, 0, 0), NOWAIT)
    PHX(3, 1, NOOP,                      NOOP,           STAGE_B(tt + 2, 1, 0), VM4)
    // tile tt+1 (buf1)
    PHX(0, 0, AREAD(0, 0, 1); BVLOAD(1), AREAD(1, 1, 1), STAGE_A(tt + 2, 0, 0), NOWAIT)
    PHX(1, 1, NOOP,                      AREAD(0, 2, 1), STAGE_A(tt + 2, 1, 0), NOWAIT)
    PHX(2, 0, NOOP,                      AREAD(1, 3, 1), STAGE_B(tt + 3, 0, 1), NOWAIT)
    PHX(3, 1, NOOP,                      NOOP,           STAGE_B(tt + 3, 1, 1), VM4)
  }
  // tail: tiles NT-2 (buf0, stage last A tile) and NT-1 (buf1, compute only)
  PHX(0, 0, AREAD(0, 0, 0); BVLOAD(0), AREAD(1, 1, 0), STAGE_A(NT - 1, 0, 1), NOWAIT)
  PHX(1, 1, NOOP,                      AREAD(0, 2, 0), STAGE_A(NT - 1, 1, 1), NOWAIT)
  PHX(2, 0, NOOP,                      AREAD(1, 3, 0), NOSTAGE, NOWAIT)
  PHX(3, 1, NOOP,                      NOOP,           NOSTAGE, VM0)
  PHX(0, 0, AREAD(0, 0, 1); BVLOAD(1), AREAD(1, 1, 1), NOSTAGE, NOWAIT)
  PHX(1, 1, NOOP,                      AREAD(0, 2, 1), NOSTAGE, NOWAIT)
  PHX(2, 0, NOOP,                      AREAD(1, 3, 1), NOSTAGE, NOWAIT)
  PHX(3, 1, NOOP,                      NOOP,           NOSTAGE, NOWAIT)

#pragma unroll
  for (int mi = 0; mi < 8; ++mi) {
#pragma unroll
    for (int ni = 0; ni < 4; ++ni) {
      const int col  = bn + wc * 64 + ni * 16 + lr;
      const int row0 = bm + wr * 128 + mi * 16 + quad * 4;
      const float bb = bias[col];
#pragma unroll
      for (int r = 0; r < 4; ++r) {
        float v = acc[mi][ni][r] + bb;
        v = fmaxf(v, 0.0f);
        obf[(size_t)(row0 + r) * N + col] = f2bf(v);
      }
    }
  }
}

// ---------------------------------------------------------------------------
// GEMM2: out[8192x1024] = resid + out1[8192x4096] @ woT^T
// R8: 256x128 tile, BK=64, 512 thr / 8 waves (4Mx2N, 64x64/wave), 96 KiB
// dbuf LDS, 2 phases/K-tile x 16 MFMA, counted VM2, grid 256 = 1/CU.
// ---------------------------------------------------------------------------
__global__ __launch_bounds__(512) void gemm2_kernel(
    const u16* __restrict__ A, const u16* __restrict__ Bt,
    const float* __restrict__ resid, float* __restrict__ out) {
  const int K = FDIM, N = DDIM;
  const int NT = K / 64;                    // 64 K-tiles
  const size_t KP = (size_t)128 * K;        // piece-1 global row offset
  __shared__ __align__(16) u16 sA[2][16384];  // 64 KB (2 bufs x 256x64)
  __shared__ __align__(16) u16 sB[2][8192];   // 32 KB (2 bufs x 128x64)

  const int tid  = threadIdx.x;
  const int lane = tid & 63;
  const int wave = tid >> 6;
  const int wr = wave >> 1, wc = wave & 1;    // 4 x 2 wave grid (64x64/wave)
  const int lr = lane & 15, quad = lane >> 4;

  const int bid = blockIdx.x;
  const int swz = (bid & 7) * 32 + (bid >> 3);
  const int bm = (swz >> 3) * 256;
  const int bn = (swz & 7) * 128;

  int lofs0, lofs1;
  const u16 *gA0, *gA1, *gB0, *gB1;
  {
    const int s0 = tid,       r0 = s0 >> 3, g0 = (s0 & 7) ^ (r0 & 7);
    const int s1 = tid + 512, r1 = s1 >> 3, g1 = (s1 & 7) ^ (r1 & 7);
    gA0 = A  + (size_t)(bm + r0) * K + g0 * 8;
    gA1 = A  + (size_t)(bm + r1) * K + g1 * 8;
    gB0 = Bt + (size_t)(bn + r0) * K + g0 * 8;   // B rows 0..63 (slot tid)
    gB1 = Bt + (size_t)(bn + r1) * K + g1 * 8;   // B rows 64..127 (tid+512)
    lofs0 = s0 * 8; lofs1 = s1 * 8;
  }

  int arow8[4];
#pragma unroll
  for (int mi = 0; mi < 4; ++mi) arow8[mi] = (wr * 64 + mi * 16 + lr) * 8;
  const int brow80 = (wc * 64 +  0 + lr) * 8;
  const int brow81 = (wc * 64 + 16 + lr) * 8;
  const int brow82 = (wc * 64 + 32 + lr) * 8;
  const int brow83 = (wc * 64 + 48 + lr) * 8;
  const int sega0 = quad ^ (lr & 7);
  const int sega1 = (4 + quad) ^ (lr & 7);

  f32x4 acc[4][4] = {};
  bf16x8 bv[4][2];

  STAGE_B(0, 0, 0)
  STAGE_A(0, 0, 0) STAGE_A(0, 1, 0)
  STAGE_B(1, 0, 1)
  asm volatile("s_waitcnt vmcnt(2)" ::: "memory");
  __builtin_amdgcn_s_barrier();

  for (int tt = 0; tt < NT - 2; tt += 2) {
    PHASE(0, 0, BVLOAD(0); STAGE_A(tt + 1, 0, 1), NOWAIT)
    PHASE(1, 0, STAGE_A(tt + 1, 1, 1); STAGE_B(tt + 2, 0, 0), VM2)
    PHASE(0, 1, BVLOAD(1); STAGE_A(tt + 2, 0, 0), NOWAIT)
    PHASE(1, 1, STAGE_A(tt + 2, 1, 0); STAGE_B(tt + 3, 0, 1), VM2)
  }
  PHASE(0, 0, BVLOAD(0); STAGE_A(NT - 1, 0, 1), NOWAIT)
  PHASE(1, 0, STAGE_A(NT - 1, 1, 1), VM0)
  PHASE(0, 1, BVLOAD(1), NOWAIT)
  PHASE(1, 1, NOSTAGE, NOWAIT)

#pragma unroll
  for (int mi = 0; mi < 4; ++mi) {
#pragma unroll
    for (int ni = 0; ni < 4; ++ni) {
      const int col  = bn + wc * 64 + ni * 16 + lr;
      const int row0 = bm + wr * 64 + mi * 16 + quad * 4;
#pragma unroll
      for (int r = 0; r < 4; ++r) {
        const size_t idx = (size_t)(row0 + r) * N + col;
        out[idx] = resid[idx] + acc[mi][ni][r];
      }
    }
  }
}

// ---------------------------------------------------------------------------
// Workspace layout (bytes):
//   hcat       [8192 x 3072] bf16              @ 0          (50331648)
//   WcatT      [4096 x 3072] bf16              @ 50331648   (25165824)
//   woT        [1024 x 4096] bf16              @ 75497472   ( 8388608)
//   out1       [8192 x 4096] bf16              @ 83886080   (67108864)
//     bucket_src [262144] i32 (aliases out1)   @ 83886080   ( 1048576)
//     cnt        [16384] i32                   @ 84934656   (   65536)
//     off        [16384] i32                   @ 85000192   (   65536)
//     cursor     [16384] i32                   @ 85065728   (   65536)
//     xq         [8192 x 1024] fp8             @ 85131264   ( 8388608)
//   (all aliased scratch consumed before GEMM1 writes out1)
// total: 150994944 bytes (144 MB)
// ---------------------------------------------------------------------------
extern "C" void kernel_launch(void* const* d_in, const int* in_sizes, int n_in,
                              void* d_out, int out_size, void* d_ws, size_t ws_size,
                              hipStream_t stream) {
  const float* hs     = (const float*)d_in[0];
  const float* weight = (const float*)d_in[1];   // [2,1024,4096]
  const float* root   = (const float*)d_in[2];   // [1024,4096]
  const float* bias   = (const float*)d_in[3];   // [4096]
  const float* wo     = (const float*)d_in[4];   // [4096,1024]
  const float* gamma  = (const float*)d_in[5];
  const float* beta   = (const float*)d_in[6];
  const int* edge_index = (const int*)d_in[7];   // [2,E]
  const int* edge_type  = (const int*)d_in[8];   // [E]
  float* out = (float*)d_out;

  char* ws = (char*)d_ws;
  u16*   hcat       = (u16*)(ws + 0);
  u16*   WcatT      = (u16*)(ws + 50331648);
  u16*   woT        = (u16*)(ws + 75497472);
  u16*   out1       = (u16*)(ws + 83886080);
  int*   bucket_src = (int*)(ws + 83886080);     // aliases out1 (consumed pre-GEMM1)
  int*   cnt        = (int*)(ws + 84934656);
  int*   off        = (int*)(ws + 85000192);
  int*   cursor     = (int*)(ws + 85065728);
  u32*   xq         = (u32*)(ws + 85131264);     // fp8 x, dense [8192][1024]

  (void)hipMemsetAsync(cnt, 0, 65536, stream);

  ln_kernel<<<NNODE, 256, 0, stream>>>(hs, gamma, beta, hcat, xq);

  cvt_transpose<<<dim3(FDIM / 32, KCAT / 32), dim3(32, 8), 0, stream>>>(
      weight, root, 2048, KCAT, FDIM, WcatT);
  cvt_transpose<<<dim3(DDIM / 32, FDIM / 32), dim3(32, 8), 0, stream>>>(
      wo, wo, FDIM, FDIM, DDIM, woT);

  count_kernel<<<E_NUM / 256, 256, 0, stream>>>(edge_index, edge_type, cnt);
  scan_kernel<<<1, 1024, 0, stream>>>(cnt, off, cursor);
  fill_kernel<<<E_NUM / 256, 256, 0, stream>>>(edge_index, edge_type, cursor, bucket_src);
  aggregate_kernel<<<NBKT / 4, 256, 0, stream>>>(cnt, off, bucket_src, xq, hcat);

  // out1 = relu([h0|h1|x] @ [W0;W1;root] + bias)   [8192 x 4096] bf16
  gemm1_kernel<<<512, 512, 0, stream>>>(hcat, WcatT, bias, out1);

  // out = hs + out1 @ wo                            [8192 x 1024] f32
  gemm2_kernel<<<256, 512, 0, stream>>>(out1, woT, hs, out);
}

// Round 4
// 475.260 us; speedup vs baseline: 1.0170x; 1.0170x over previous
//
#include <hip/hip_runtime.h>

// ---------------------------------------------------------------------------
// T5GNNAdapt: LN -> RGCN scatter-mean (2 relations) -> [h0|h1|x] @ [W0;W1;root]
//             + bias -> relu -> @wo -> + residual
// Shapes: B=8,S=1024,D=1024,F=4096,E=262144,N=B*S=8192, K_cat=3072
// R7: gemm1 -> 256^2 8-phase counted-vmcnt template: 190us, MfmaUtil 47.7%.
// R8: gemm2 -> same template (256x128, 2 phases/K-tile, VM2): total 501->474.
// R9: FAILED: gemm1 A-frag prefetch (sched_barrier restructure) -14%->reverted.
//     aggregate wave-per-bucket: neutral (gather-BW bound, kept - simpler).
// R10: (a) gemm1 loop reverted to R8 exactly; (b) gemm1 epilogue re-tiled
//     through LDS (scalar u16 strided stores -> dwordx4 coalesced, LDS is
//     dead post-loop); (c) count fused into ln (one fewer dispatch);
//     (d) cvt_transposes moved after aggregate (keep xq L2-warm for gather).
// ---------------------------------------------------------------------------

typedef unsigned short u16;
typedef unsigned int   u32;
typedef __attribute__((ext_vector_type(8))) short bf16x8;
typedef __attribute__((ext_vector_type(4))) float f32x4;
typedef __attribute__((ext_vector_type(2))) float f32x2;

#define E_NUM  262144
#define NNODE  8192
#define NBKT   (2 * NNODE)      // 16384 (rel,dst) buckets
#define DDIM   1024
#define FDIM   4096
#define KCAT   3072
#define LN_EPS 1e-6f

struct alignas(8) u16x4 { u16 x, y, z, w; };

__device__ __forceinline__ u16 f2bf(float f) {
  u32 u = __float_as_uint(f);
  u32 r = u + 0x7fffu + ((u >> 16) & 1u);   // RNE
  return (u16)(r >> 16);
}
__device__ __forceinline__ float bf2f(u16 h) {
  return __uint_as_float(((u32)h) << 16);
}

// ---- fp8 e4m3fn (OCP) encode/decode; HW cvt when available ---------------
__device__ __forceinline__ u32 enc_fp8_1(float f) {
  u32 u = __float_as_uint(f);
  u32 s = u >> 31;
  u32 mag = u & 0x7fffffffu;
  mag = mag + 0x7ffffu + ((mag >> 20) & 1u);          // RNE to 3 mant bits
  if (mag > 0x43e00000u) mag = 0x43e00000u;           // clamp to 448
  u32 e = mag >> 23;
  return (e <= 120u) ? 0u
                     : ((s << 7) | ((e - 120u) << 3) | ((mag >> 20) & 7u));
}

__device__ __forceinline__ u32 pack4_fp8(float a, float b, float c, float d) {
#if __has_builtin(__builtin_amdgcn_cvt_pk_fp8_f32)
  int v = 0;
  v = __builtin_amdgcn_cvt_pk_fp8_f32(a, b, v, false);  // bytes 0,1
  v = __builtin_amdgcn_cvt_pk_fp8_f32(c, d, v, true);   // bytes 2,3
  return (u32)v;
#else
  return enc_fp8_1(a) | (enc_fp8_1(b) << 8) | (enc_fp8_1(c) << 16) |
         (enc_fp8_1(d) << 24);
#endif
}

__device__ __forceinline__ float dec_fp8_1(u32 b) {
  u32 e = (b >> 3) & 15u;
  u32 f = ((b & 0x80u) << 24) | ((e + 120u) << 23) | ((b & 7u) << 20);
  return e ? __uint_as_float(f) : 0.0f;
}

__device__ __forceinline__ void acc4_fp8(float* a, u32 q) {
#if __has_builtin(__builtin_amdgcn_cvt_pk_f32_fp8)
  f32x2 p0 = __builtin_amdgcn_cvt_pk_f32_fp8((int)q, false);
  f32x2 p1 = __builtin_amdgcn_cvt_pk_f32_fp8((int)q, true);
  a[0] += p0.x; a[1] += p0.y; a[2] += p1.x; a[3] += p1.y;
#else
  a[0] += dec_fp8_1(q);       a[1] += dec_fp8_1(q >> 8);
  a[2] += dec_fp8_1(q >> 16); a[3] += dec_fp8_1(q >> 24);
#endif
}

__device__ __forceinline__ void acc16_fp8(float* a, uint4 x) {
  acc4_fp8(a + 0,  x.x); acc4_fp8(a + 4,  x.y);
  acc4_fp8(a + 8,  x.z); acc4_fp8(a + 12, x.w);
}

// 16-byte global -> LDS async copy (wave-uniform LDS base + lane*16 layout)
#define GLD16(gp, lp)                                              \
  __builtin_amdgcn_global_load_lds(                                \
      (__attribute__((address_space(1))) u32*)(gp),                \
      (__attribute__((address_space(3))) u32*)(lp), 16, 0, 0)

// ---------------------------------------------------------------------------
// K1: LayerNorm (one-pass) + fused edge-count. Writes bf16 x into
// hcat[:, 2048:3072] AND fp8 copy into dense xq[8192x1024]. Lanes 0-31 of
// each block also count 32 edges into cnt (R10: count_kernel fused away).
// ---------------------------------------------------------------------------
__global__ void ln_kernel(const float* __restrict__ hs,
                          const float* __restrict__ gamma,
                          const float* __restrict__ beta,
                          u16* __restrict__ hcat,
                          u32* __restrict__ xq,
                          const int* __restrict__ edge_index,
                          const int* __restrict__ edge_type,
                          int* __restrict__ cnt) {
  const int row = blockIdx.x;
  const int tid = threadIdx.x;
  const float4 v = ((const float4*)(hs + (size_t)row * DDIM))[tid];

  if (tid < 32) {                       // fused count: 32 edges per block
    const int e = (row << 5) + tid;
    const int d = edge_index[E_NUM + e];
    const int r = edge_type[e];
    atomicAdd(&cnt[r * NNODE + d], 1);
  }

  __shared__ float r1[256], r2[256];
  r1[tid] = v.x + v.y + v.z + v.w;
  r2[tid] = v.x * v.x + v.y * v.y + v.z * v.z + v.w * v.w;
  __syncthreads();
  for (int st = 128; st > 0; st >>= 1) {
    if (tid < st) { r1[tid] += r1[tid + st]; r2[tid] += r2[tid + st]; }
    __syncthreads();
  }
  const float mean = r1[0] * (1.0f / DDIM);
  const float var  = r2[0] * (1.0f / DDIM) - mean * mean;
  const float rs   = rsqrtf(var + LN_EPS);

  const int base = tid * 4;
  const float4 g = *(const float4*)(gamma + base);
  const float4 b = *(const float4*)(beta + base);
  const float o0 = (v.x - mean) * rs * g.x + b.x;
  const float o1 = (v.y - mean) * rs * g.y + b.y;
  const float o2 = (v.z - mean) * rs * g.z + b.z;
  const float o3 = (v.w - mean) * rs * g.w + b.w;
  u16x4 o;
  o.x = f2bf(o0); o.y = f2bf(o1); o.z = f2bf(o2); o.w = f2bf(o3);
  *(u16x4*)(hcat + (size_t)row * KCAT + 2048 + base) = o;
  xq[row * 256 + tid] = pack4_fp8(o0, o1, o2, o3);
}

// ---------------------------------------------------------------------------
// K2: f32 [K,N] -> bf16 [N,K] transpose (stitches two sources along K).
// ---------------------------------------------------------------------------
__global__ void cvt_transpose(const float* __restrict__ srcA,
                              const float* __restrict__ srcB,
                              int splitK, int K, int N,
                              u16* __restrict__ dst) {
  __shared__ float tile[32][33];
  const int n0 = blockIdx.x * 32, k0 = blockIdx.y * 32;
  const int tx = threadIdx.x, ty = threadIdx.y;
  for (int i = ty; i < 32; i += 8) {
    const int k = k0 + i;
    const float v = (k < splitK) ? srcA[(size_t)k * N + n0 + tx]
                                 : srcB[(size_t)(k - splitK) * N + n0 + tx];
    tile[i][tx] = v;
  }
  __syncthreads();
  for (int i = ty; i < 32; i += 8) {
    dst[(size_t)(n0 + i) * K + k0 + tx] = f2bf(tile[tx][i]);
  }
}

// ---------------------------------------------------------------------------
// K3b: exclusive prefix sum over 16384 counts (single block, 1024 thr).
// ---------------------------------------------------------------------------
__global__ __launch_bounds__(1024) void scan_kernel(const int* __restrict__ cnt,
                                                    int* __restrict__ off,
                                                    int* __restrict__ cursor) {
  __shared__ int partial[1024];
  const int tid  = threadIdx.x;
  const int base = tid * 16;
  int local[16];
  int s = 0;
#pragma unroll
  for (int i = 0; i < 16; ++i) { local[i] = s; s += cnt[base + i]; }
  partial[tid] = s;
  __syncthreads();
  for (int st = 1; st < 1024; st <<= 1) {
    const int v = (tid >= st) ? partial[tid - st] : 0;
    __syncthreads();
    partial[tid] += v;
    __syncthreads();
  }
  const int pre = (tid == 0) ? 0 : partial[tid - 1];
#pragma unroll
  for (int i = 0; i < 16; ++i) {
    const int o = pre + local[i];
    off[base + i]    = o;
    cursor[base + i] = o;
  }
}

// ---------------------------------------------------------------------------
// K3c: scatter edge SOURCE ids into buckets (4B per edge, not row data).
// ---------------------------------------------------------------------------
__global__ void fill_kernel(const int* __restrict__ edge_index,
                            const int* __restrict__ edge_type,
                            int* __restrict__ cursor,
                            int* __restrict__ bucket_src) {
  const int e = blockIdx.x * 256 + threadIdx.x;
  const int s = edge_index[e];
  const int d = edge_index[E_NUM + e];
  const int r = edge_type[e];
  const int pos = atomicAdd(&cursor[r * NNODE + d], 1);
  bucket_src[pos] = s;
}

// ---------------------------------------------------------------------------
// K4: wave-per-bucket aggregation. One 64-lane wave owns one (rel,node)
// bucket; lane covers 16 cols (dwordx4 of fp8). Edge ids held in a register
// and broadcast via __shfl — no LDS, no __syncthreads. 4 buckets/block.
// ---------------------------------------------------------------------------
__global__ __launch_bounds__(256) void aggregate_kernel(
    const int* __restrict__ cnt, const int* __restrict__ off,
    const int* __restrict__ bucket_src, const u32* __restrict__ xq,
    u16* __restrict__ hcat) {
  const int b    = blockIdx.x * 4 + (threadIdx.x >> 6);  // bucket id
  const int lane = threadIdx.x & 63;
  const int r    = b >> 13;
  const int node = b & (NNODE - 1);
  const int n     = cnt[b];
  const int start = off[b];

  float a[16] = {};

  for (int j0 = 0; j0 < n; j0 += 64) {
    const int m = min(n - j0, 64);
    const int myid = (lane < m) ? bucket_src[start + j0 + lane] : 0;
    int j = 0;
    for (; j + 3 < m; j += 4) {
      const int s0 = __shfl(myid, j,     64);
      const int s1 = __shfl(myid, j + 1, 64);
      const int s2 = __shfl(myid, j + 2, 64);
      const int s3 = __shfl(myid, j + 3, 64);
      const uint4 x0 = *(const uint4*)(xq + s0 * 256 + lane * 4);
      const uint4 x1 = *(const uint4*)(xq + s1 * 256 + lane * 4);
      const uint4 x2 = *(const uint4*)(xq + s2 * 256 + lane * 4);
      const uint4 x3 = *(const uint4*)(xq + s3 * 256 + lane * 4);
      acc16_fp8(a, x0); acc16_fp8(a, x1);
      acc16_fp8(a, x2); acc16_fp8(a, x3);
    }
    for (; j < m; ++j) {
      const int s0 = __shfl(myid, j, 64);
      const uint4 x0 = *(const uint4*)(xq + s0 * 256 + lane * 4);
      acc16_fp8(a, x0);
    }
  }

  const float inv = 1.0f / fmaxf((float)n, 1.0f);
  uint4 o0, o1;
  o0.x = (u32)f2bf(a[0] * inv)  | ((u32)f2bf(a[1] * inv)  << 16);
  o0.y = (u32)f2bf(a[2] * inv)  | ((u32)f2bf(a[3] * inv)  << 16);
  o0.z = (u32)f2bf(a[4] * inv)  | ((u32)f2bf(a[5] * inv)  << 16);
  o0.w = (u32)f2bf(a[6] * inv)  | ((u32)f2bf(a[7] * inv)  << 16);
  o1.x = (u32)f2bf(a[8] * inv)  | ((u32)f2bf(a[9] * inv)  << 16);
  o1.y = (u32)f2bf(a[10] * inv) | ((u32)f2bf(a[11] * inv) << 16);
  o1.z = (u32)f2bf(a[12] * inv) | ((u32)f2bf(a[13] * inv) << 16);
  o1.w = (u32)f2bf(a[14] * inv) | ((u32)f2bf(a[15] * inv) << 16);
  u16* dp = hcat + (size_t)node * KCAT + (size_t)r * DDIM + lane * 16;
  *(uint4*)(dp)     = o0;
  *(uint4*)(dp + 8) = o1;
}

// ---------------------------------------------------------------------------
// Shared 8-phase GEMM machinery (expanded in gemm kernels; names resolve to
// kernel-local variables at expansion site).
// ---------------------------------------------------------------------------

#define MF16(a, b, c) __builtin_amdgcn_mfma_f32_16x16x32_bf16(a, b, c, 0, 0, 0)

#define STAGE_A(t, p, b)                                                   \
  { GLD16(gA0 + (size_t)(t) * 64 + (size_t)(p) * KP,                       \
          &sA[b][(p) * 8192 + lofs0]);                                     \
    GLD16(gA1 + (size_t)(t) * 64 + (size_t)(p) * KP,                       \
          &sA[b][(p) * 8192 + lofs1]); }

#define STAGE_B(t, p, b)                                                   \
  { GLD16(gB0 + (size_t)(t) * 64 + (size_t)(p) * KP,                       \
          &sB[b][(p) * 8192 + lofs0]);                                     \
    GLD16(gB1 + (size_t)(t) * 64 + (size_t)(p) * KP,                       \
          &sB[b][(p) * 8192 + lofs1]); }

#define BVLOAD(b)                                                          \
  { const bf16x8* pB_ = (const bf16x8*)sB[b];                              \
    bv[0][0] = pB_[brow80 + sega0]; bv[0][1] = pB_[brow80 + sega1];        \
    bv[1][0] = pB_[brow81 + sega0]; bv[1][1] = pB_[brow81 + sega1];        \
    bv[2][0] = pB_[brow82 + sega0]; bv[2][1] = pB_[brow82 + sega1];        \
    bv[3][0] = pB_[brow83 + sega0]; bv[3][1] = pB_[brow83 + sega1]; }

#define NOWAIT ((void)0)
#define NOSTAGE ((void)0)
#define VM4 asm volatile("s_waitcnt vmcnt(4)" ::: "memory")
#define VM2 asm volatile("s_waitcnt vmcnt(2)" ::: "memory")
#define VM0 asm volatile("s_waitcnt vmcnt(0)" ::: "memory")

#define PHASE(Q, BUFI, STAGE, ENDW)                                        \
  { const bf16x8* pA_ = (const bf16x8*)sA[BUFI];                           \
    bf16x8 a00 = pA_[arow8[2 * (Q)] + sega0];                              \
    bf16x8 a01 = pA_[arow8[2 * (Q)] + sega1];                              \
    bf16x8 a10 = pA_[arow8[2 * (Q) + 1] + sega0];                          \
    bf16x8 a11 = pA_[arow8[2 * (Q) + 1] + sega1];                          \
    STAGE;                                                                 \
    __builtin_amdgcn_s_barrier();                                          \
    asm volatile("s_waitcnt lgkmcnt(0)" ::: "memory");                     \
    __builtin_amdgcn_s_setprio(1);                                         \
    _Pragma("unroll")                                                      \
    for (int ni = 0; ni < 4; ++ni) {                                       \
      acc[2 * (Q)][ni]     = MF16(a00, bv[ni][0], acc[2 * (Q)][ni]);       \
      acc[2 * (Q)][ni]     = MF16(a01, bv[ni][1], acc[2 * (Q)][ni]);       \
      acc[2 * (Q) + 1][ni] = MF16(a10, bv[ni][0], acc[2 * (Q) + 1][ni]);   \
      acc[2 * (Q) + 1][ni] = MF16(a11, bv[ni][1], acc[2 * (Q) + 1][ni]);   \
    }                                                                      \
    __builtin_amdgcn_s_setprio(0);                                         \
    ENDW;                                                                  \
    __builtin_amdgcn_s_barrier(); }

// ---------------------------------------------------------------------------
// GEMM1: out1[8192x4096] = bf16(relu(hcat[8192x3072] @ WcatT^T + bias))
// 256x256 tile, BK=64, 512 thr / 8 waves (2Mx4N), 128 KiB dbuf LDS,
// 8-phase counted-vmcnt schedule; vmcnt(4) only at phases 4/8 (R8: 189.7us).
// R10: epilogue re-tiled through LDS — LDS is dead after the K-loop; stage
// bias+relu+f2bf into [128][264] u16 (pad keeps 16B align, spreads banks),
// copy out as dwordx4 (1KB/wave-instr), two rounds (wr=0 rows, wr=1 rows).
// ---------------------------------------------------------------------------
__global__ __launch_bounds__(512) void gemm1_kernel(
    const u16* __restrict__ A, const u16* __restrict__ Bt,
    const float* __restrict__ bias, u16* __restrict__ obf) {
  const int K = KCAT, N = FDIM;
  const int NT = K / 64;                    // 48 K-tiles
  const size_t KP = (size_t)128 * K;        // piece-1 global row offset
  __shared__ __align__(16) u16 smem[65536];   // 128 KB
  u16 (*sA)[16384] = (u16(*)[16384])(smem);          // 2 bufs x 256x64 bf16
  u16 (*sB)[16384] = (u16(*)[16384])(smem + 32768);  // 2 bufs x 256x64 bf16

  const int tid  = threadIdx.x;
  const int lane = tid & 63;
  const int wave = tid >> 6;
  const int wr = wave >> 2, wc = wave & 3;    // 2 x 4 wave grid
  const int lr = lane & 15, quad = lane >> 4;

  const int bid = blockIdx.x;
  const int swz = (bid & 7) * 64 + (bid >> 3);
  const int bm = (swz >> 4) * 256;
  const int bn = (swz & 15) * 256;

  int lofs0, lofs1;
  const u16 *gA0, *gA1, *gB0, *gB1;
  {
    const int s0 = tid,       r0 = s0 >> 3, g0 = (s0 & 7) ^ (r0 & 7);
    const int s1 = tid + 512, r1 = s1 >> 3, g1 = (s1 & 7) ^ (r1 & 7);
    gA0 = A  + (size_t)(bm + r0) * K + g0 * 8;
    gA1 = A  + (size_t)(bm + r1) * K + g1 * 8;
    gB0 = Bt + (size_t)(bn + r0) * K + g0 * 8;
    gB1 = Bt + (size_t)(bn + r1) * K + g1 * 8;
    lofs0 = s0 * 8; lofs1 = s1 * 8;
  }

  int arow8[8];
#pragma unroll
  for (int mi = 0; mi < 8; ++mi) arow8[mi] = (wr * 128 + mi * 16 + lr) * 8;
  const int brow80 = (wc * 64 +  0 + lr) * 8;
  const int brow81 = (wc * 64 + 16 + lr) * 8;
  const int brow82 = (wc * 64 + 32 + lr) * 8;
  const int brow83 = (wc * 64 + 48 + lr) * 8;
  const int sega0 = quad ^ (lr & 7);
  const int sega1 = (4 + quad) ^ (lr & 7);

  f32x4 acc[8][4] = {};
  bf16x8 bv[4][2];

  STAGE_B(0, 0, 0) STAGE_B(0, 1, 0)
  STAGE_A(0, 0, 0) STAGE_A(0, 1, 0)
  STAGE_B(1, 0, 1) STAGE_B(1, 1, 1)
  asm volatile("s_waitcnt vmcnt(4)" ::: "memory");
  __builtin_amdgcn_s_barrier();

  for (int tt = 0; tt < NT - 2; tt += 2) {
    PHASE(0, 0, BVLOAD(0); STAGE_A(tt + 1, 0, 1), NOWAIT)
    PHASE(1, 0, STAGE_A(tt + 1, 1, 1), NOWAIT)
    PHASE(2, 0, STAGE_B(tt + 2, 0, 0), NOWAIT)
    PHASE(3, 0, STAGE_B(tt + 2, 1, 0), VM4)
    PHASE(0, 1, BVLOAD(1); STAGE_A(tt + 2, 0, 0), NOWAIT)
    PHASE(1, 1, STAGE_A(tt + 2, 1, 0), NOWAIT)
    PHASE(2, 1, STAGE_B(tt + 3, 0, 1), NOWAIT)
    PHASE(3, 1, STAGE_B(tt + 3, 1, 1), VM4)
  }
  PHASE(0, 0, BVLOAD(0); STAGE_A(NT - 1, 0, 1), NOWAIT)
  PHASE(1, 0, STAGE_A(NT - 1, 1, 1), NOWAIT)
  PHASE(2, 0, NOSTAGE, NOWAIT)
  PHASE(3, 0, NOSTAGE, VM0)
  PHASE(0, 1, BVLOAD(1), NOWAIT)
  PHASE(1, 1, NOSTAGE, NOWAIT)
  PHASE(2, 1, NOSTAGE, NOWAIT)
  PHASE(3, 1, NOSTAGE, NOWAIT)

  // --- R10 epilogue: bias+relu+f2bf -> LDS [128][264] -> dwordx4 stores ---
  const int CPAD = 264;                       // 264*2B row pitch: 16B-aligned
#pragma unroll
  for (int h = 0; h < 2; ++h) {
    if (wr == h) {
#pragma unroll
      for (int mi = 0; mi < 8; ++mi) {
        const int lrow = mi * 16 + quad * 4;
#pragma unroll
        for (int ni = 0; ni < 4; ++ni) {
          const int col = wc * 64 + ni * 16 + lr;
          const float bb = bias[bn + col];
#pragma unroll
          for (int r = 0; r < 4; ++r) {
            const float v = acc[mi][ni][r] + bb;
            smem[(lrow + r) * CPAD + col] = f2bf(fmaxf(v, 0.0f));
          }
        }
      }
    }
    __syncthreads();
#pragma unroll
    for (int i = 0; i < 8; ++i) {
      const int chunk = tid + 512 * i;        // 4096 chunks of 16B
      const int row = chunk >> 5;             // 0..127
      const int seg = chunk & 31;             // 0..31
      const uint4 val = *(const uint4*)(smem + row * CPAD + seg * 8);
      *(uint4*)(obf + (size_t)(bm + h * 128 + row) * N + bn + seg * 8) = val;
    }
    __syncthreads();
  }
}

// ---------------------------------------------------------------------------
// GEMM2: out[8192x1024] = resid + out1[8192x4096] @ woT^T
// R8: 256x128 tile, BK=64, 512 thr / 8 waves (4Mx2N, 64x64/wave), 96 KiB
// dbuf LDS, 2 phases/K-tile x 16 MFMA, counted VM2, grid 256 = 1/CU.
// ---------------------------------------------------------------------------
__global__ __launch_bounds__(512) void gemm2_kernel(
    const u16* __restrict__ A, const u16* __restrict__ Bt,
    const float* __restrict__ resid, float* __restrict__ out) {
  const int K = FDIM, N = DDIM;
  const int NT = K / 64;                    // 64 K-tiles
  const size_t KP = (size_t)128 * K;        // piece-1 global row offset
  __shared__ __align__(16) u16 sA[2][16384];  // 64 KB (2 bufs x 256x64)
  __shared__ __align__(16) u16 sB[2][8192];   // 32 KB (2 bufs x 128x64)

  const int tid  = threadIdx.x;
  const int lane = tid & 63;
  const int wave = tid >> 6;
  const int wr = wave >> 1, wc = wave & 1;    // 4 x 2 wave grid (64x64/wave)
  const int lr = lane & 15, quad = lane >> 4;

  const int bid = blockIdx.x;
  const int swz = (bid & 7) * 32 + (bid >> 3);
  const int bm = (swz >> 3) * 256;
  const int bn = (swz & 7) * 128;

  int lofs0, lofs1;
  const u16 *gA0, *gA1, *gB0, *gB1;
  {
    const int s0 = tid,       r0 = s0 >> 3, g0 = (s0 & 7) ^ (r0 & 7);
    const int s1 = tid + 512, r1 = s1 >> 3, g1 = (s1 & 7) ^ (r1 & 7);
    gA0 = A  + (size_t)(bm + r0) * K + g0 * 8;
    gA1 = A  + (size_t)(bm + r1) * K + g1 * 8;
    gB0 = Bt + (size_t)(bn + r0) * K + g0 * 8;   // B rows 0..63 (slot tid)
    gB1 = Bt + (size_t)(bn + r1) * K + g1 * 8;   // B rows 64..127 (tid+512)
    lofs0 = s0 * 8; lofs1 = s1 * 8;
  }

  int arow8[4];
#pragma unroll
  for (int mi = 0; mi < 4; ++mi) arow8[mi] = (wr * 64 + mi * 16 + lr) * 8;
  const int brow80 = (wc * 64 +  0 + lr) * 8;
  const int brow81 = (wc * 64 + 16 + lr) * 8;
  const int brow82 = (wc * 64 + 32 + lr) * 8;
  const int brow83 = (wc * 64 + 48 + lr) * 8;
  const int sega0 = quad ^ (lr & 7);
  const int sega1 = (4 + quad) ^ (lr & 7);

  f32x4 acc[4][4] = {};
  bf16x8 bv[4][2];

  STAGE_B(0, 0, 0)
  STAGE_A(0, 0, 0) STAGE_A(0, 1, 0)
  STAGE_B(1, 0, 1)
  asm volatile("s_waitcnt vmcnt(2)" ::: "memory");
  __builtin_amdgcn_s_barrier();

  for (int tt = 0; tt < NT - 2; tt += 2) {
    PHASE(0, 0, BVLOAD(0); STAGE_A(tt + 1, 0, 1), NOWAIT)
    PHASE(1, 0, STAGE_A(tt + 1, 1, 1); STAGE_B(tt + 2, 0, 0), VM2)
    PHASE(0, 1, BVLOAD(1); STAGE_A(tt + 2, 0, 0), NOWAIT)
    PHASE(1, 1, STAGE_A(tt + 2, 1, 0); STAGE_B(tt + 3, 0, 1), VM2)
  }
  PHASE(0, 0, BVLOAD(0); STAGE_A(NT - 1, 0, 1), NOWAIT)
  PHASE(1, 0, STAGE_A(NT - 1, 1, 1), VM0)
  PHASE(0, 1, BVLOAD(1), NOWAIT)
  PHASE(1, 1, NOSTAGE, NOWAIT)

#pragma unroll
  for (int mi = 0; mi < 4; ++mi) {
#pragma unroll
    for (int ni = 0; ni < 4; ++ni) {
      const int col  = bn + wc * 64 + ni * 16 + lr;
      const int row0 = bm + wr * 64 + mi * 16 + quad * 4;
#pragma unroll
      for (int r = 0; r < 4; ++r) {
        const size_t idx = (size_t)(row0 + r) * N + col;
        out[idx] = resid[idx] + acc[mi][ni][r];
      }
    }
  }
}

// ---------------------------------------------------------------------------
// Workspace layout (bytes):
//   hcat       [8192 x 3072] bf16              @ 0          (50331648)
//   WcatT      [4096 x 3072] bf16              @ 50331648   (25165824)
//   woT        [1024 x 4096] bf16              @ 75497472   ( 8388608)
//   out1       [8192 x 4096] bf16              @ 83886080   (67108864)
//     bucket_src [262144] i32 (aliases out1)   @ 83886080   ( 1048576)
//     cnt        [16384] i32                   @ 84934656   (   65536)
//     off        [16384] i32                   @ 85000192   (   65536)
//     cursor     [16384] i32                   @ 85065728   (   65536)
//     xq         [8192 x 1024] fp8             @ 85131264   ( 8388608)
//   (all aliased scratch consumed before GEMM1 writes out1)
// total: 150994944 bytes (144 MB)
// ---------------------------------------------------------------------------
extern "C" void kernel_launch(void* const* d_in, const int* in_sizes, int n_in,
                              void* d_out, int out_size, void* d_ws, size_t ws_size,
                              hipStream_t stream) {
  const float* hs     = (const float*)d_in[0];
  const float* weight = (const float*)d_in[1];   // [2,1024,4096]
  const float* root   = (const float*)d_in[2];   // [1024,4096]
  const float* bias   = (const float*)d_in[3];   // [4096]
  const float* wo     = (const float*)d_in[4];   // [4096,1024]
  const float* gamma  = (const float*)d_in[5];
  const float* beta   = (const float*)d_in[6];
  const int* edge_index = (const int*)d_in[7];   // [2,E]
  const int* edge_type  = (const int*)d_in[8];   // [E]
  float* out = (float*)d_out;

  char* ws = (char*)d_ws;
  u16*   hcat       = (u16*)(ws + 0);
  u16*   WcatT      = (u16*)(ws + 50331648);
  u16*   woT        = (u16*)(ws + 75497472);
  u16*   out1       = (u16*)(ws + 83886080);
  int*   bucket_src = (int*)(ws + 83886080);     // aliases out1 (consumed pre-GEMM1)
  int*   cnt        = (int*)(ws + 84934656);
  int*   off        = (int*)(ws + 85000192);
  int*   cursor     = (int*)(ws + 85065728);
  u32*   xq         = (u32*)(ws + 85131264);     // fp8 x, dense [8192][1024]

  (void)hipMemsetAsync(cnt, 0, 65536, stream);

  // LN + fused edge count
  ln_kernel<<<NNODE, 256, 0, stream>>>(hs, gamma, beta, hcat, xq,
                                       edge_index, edge_type, cnt);

  scan_kernel<<<1, 1024, 0, stream>>>(cnt, off, cursor);
  fill_kernel<<<E_NUM / 256, 256, 0, stream>>>(edge_index, edge_type, cursor, bucket_src);
  aggregate_kernel<<<NBKT / 4, 256, 0, stream>>>(cnt, off, bucket_src, xq, hcat);

  // weight transposes after aggregate: keeps xq L2-warm for the gather above
  cvt_transpose<<<dim3(FDIM / 32, KCAT / 32), dim3(32, 8), 0, stream>>>(
      weight, root, 2048, KCAT, FDIM, WcatT);
  cvt_transpose<<<dim3(DDIM / 32, FDIM / 32), dim3(32, 8), 0, stream>>>(
      wo, wo, FDIM, FDIM, DDIM, woT);

  // out1 = relu([h0|h1|x] @ [W0;W1;root] + bias)   [8192 x 4096] bf16
  gemm1_kernel<<<512, 512, 0, stream>>>(hcat, WcatT, bias, out1);

  // out = hs + out1 @ wo                            [8192 x 1024] f32
  gemm2_kernel<<<256, 512, 0, stream>>>(out1, woT, hs, out);
}

// Round 5
// 459.197 us; speedup vs baseline: 1.0525x; 1.0350x over previous
//
#include <hip/hip_runtime.h>

// ---------------------------------------------------------------------------
// T5GNNAdapt: LN -> RGCN scatter-mean (2 relations) -> [h0|h1|x] @ [W0;W1;root]
//             + bias -> relu -> @wo -> + residual
// Shapes: B=8,S=1024,D=1024,F=4096,E=262144,N=B*S=8192, K_cat=3072
// R7:  gemm1 -> 256^2 8-phase counted-vmcnt template: 190us, MfmaUtil 47.7%.
// R8:  gemm2 -> same template (256x128, 2 phases/K-tile, VM2).
// R9:  FAILED gemm1 A-prefetch restructure (reverted). aggregate wave/bucket.
// R10: gemm1 LDS epilogue (184.4us, MfmaUtil 50.5%); count fused into ln.
// R11: (a) PHASE: forced lgkmcnt(0) drain removed — compiler emits fine-
//      grained lgkmcnt(N) per MFMA dependency (m97 evidence); zero-cost
//      asm memory fences after each s_barrier prevent cross-barrier load
//      hoisting (WAR race guard). (b) gemm2 epilogue re-tiled through LDS
//      (f32 [128][132], float4 resid+store, 2 row-half rounds).
// ---------------------------------------------------------------------------

typedef unsigned short u16;
typedef unsigned int   u32;
typedef __attribute__((ext_vector_type(8))) short bf16x8;
typedef __attribute__((ext_vector_type(4))) float f32x4;
typedef __attribute__((ext_vector_type(2))) float f32x2;

#define E_NUM  262144
#define NNODE  8192
#define NBKT   (2 * NNODE)      // 16384 (rel,dst) buckets
#define DDIM   1024
#define FDIM   4096
#define KCAT   3072
#define LN_EPS 1e-6f

struct alignas(8) u16x4 { u16 x, y, z, w; };

__device__ __forceinline__ u16 f2bf(float f) {
  u32 u = __float_as_uint(f);
  u32 r = u + 0x7fffu + ((u >> 16) & 1u);   // RNE
  return (u16)(r >> 16);
}
__device__ __forceinline__ float bf2f(u16 h) {
  return __uint_as_float(((u32)h) << 16);
}

// ---- fp8 e4m3fn (OCP) encode/decode; HW cvt when available ---------------
__device__ __forceinline__ u32 enc_fp8_1(float f) {
  u32 u = __float_as_uint(f);
  u32 s = u >> 31;
  u32 mag = u & 0x7fffffffu;
  mag = mag + 0x7ffffu + ((mag >> 20) & 1u);          // RNE to 3 mant bits
  if (mag > 0x43e00000u) mag = 0x43e00000u;           // clamp to 448
  u32 e = mag >> 23;
  return (e <= 120u) ? 0u
                     : ((s << 7) | ((e - 120u) << 3) | ((mag >> 20) & 7u));
}

__device__ __forceinline__ u32 pack4_fp8(float a, float b, float c, float d) {
#if __has_builtin(__builtin_amdgcn_cvt_pk_fp8_f32)
  int v = 0;
  v = __builtin_amdgcn_cvt_pk_fp8_f32(a, b, v, false);  // bytes 0,1
  v = __builtin_amdgcn_cvt_pk_fp8_f32(c, d, v, true);   // bytes 2,3
  return (u32)v;
#else
  return enc_fp8_1(a) | (enc_fp8_1(b) << 8) | (enc_fp8_1(c) << 16) |
         (enc_fp8_1(d) << 24);
#endif
}

__device__ __forceinline__ float dec_fp8_1(u32 b) {
  u32 e = (b >> 3) & 15u;
  u32 f = ((b & 0x80u) << 24) | ((e + 120u) << 23) | ((b & 7u) << 20);
  return e ? __uint_as_float(f) : 0.0f;
}

__device__ __forceinline__ void acc4_fp8(float* a, u32 q) {
#if __has_builtin(__builtin_amdgcn_cvt_pk_f32_fp8)
  f32x2 p0 = __builtin_amdgcn_cvt_pk_f32_fp8((int)q, false);
  f32x2 p1 = __builtin_amdgcn_cvt_pk_f32_fp8((int)q, true);
  a[0] += p0.x; a[1] += p0.y; a[2] += p1.x; a[3] += p1.y;
#else
  a[0] += dec_fp8_1(q);       a[1] += dec_fp8_1(q >> 8);
  a[2] += dec_fp8_1(q >> 16); a[3] += dec_fp8_1(q >> 24);
#endif
}

__device__ __forceinline__ void acc16_fp8(float* a, uint4 x) {
  acc4_fp8(a + 0,  x.x); acc4_fp8(a + 4,  x.y);
  acc4_fp8(a + 8,  x.z); acc4_fp8(a + 12, x.w);
}

// 16-byte global -> LDS async copy (wave-uniform LDS base + lane*16 layout)
#define GLD16(gp, lp)                                              \
  __builtin_amdgcn_global_load_lds(                                \
      (__attribute__((address_space(1))) u32*)(gp),                \
      (__attribute__((address_space(3))) u32*)(lp), 16, 0, 0)

// ---------------------------------------------------------------------------
// K1: LayerNorm (one-pass) + fused edge-count. Writes bf16 x into
// hcat[:, 2048:3072] AND fp8 copy into dense xq[8192x1024]. Lanes 0-31 of
// each block also count 32 edges into cnt.
// ---------------------------------------------------------------------------
__global__ void ln_kernel(const float* __restrict__ hs,
                          const float* __restrict__ gamma,
                          const float* __restrict__ beta,
                          u16* __restrict__ hcat,
                          u32* __restrict__ xq,
                          const int* __restrict__ edge_index,
                          const int* __restrict__ edge_type,
                          int* __restrict__ cnt) {
  const int row = blockIdx.x;
  const int tid = threadIdx.x;
  const float4 v = ((const float4*)(hs + (size_t)row * DDIM))[tid];

  if (tid < 32) {                       // fused count: 32 edges per block
    const int e = (row << 5) + tid;
    const int d = edge_index[E_NUM + e];
    const int r = edge_type[e];
    atomicAdd(&cnt[r * NNODE + d], 1);
  }

  __shared__ float r1[256], r2[256];
  r1[tid] = v.x + v.y + v.z + v.w;
  r2[tid] = v.x * v.x + v.y * v.y + v.z * v.z + v.w * v.w;
  __syncthreads();
  for (int st = 128; st > 0; st >>= 1) {
    if (tid < st) { r1[tid] += r1[tid + st]; r2[tid] += r2[tid + st]; }
    __syncthreads();
  }
  const float mean = r1[0] * (1.0f / DDIM);
  const float var  = r2[0] * (1.0f / DDIM) - mean * mean;
  const float rs   = rsqrtf(var + LN_EPS);

  const int base = tid * 4;
  const float4 g = *(const float4*)(gamma + base);
  const float4 b = *(const float4*)(beta + base);
  const float o0 = (v.x - mean) * rs * g.x + b.x;
  const float o1 = (v.y - mean) * rs * g.y + b.y;
  const float o2 = (v.z - mean) * rs * g.z + b.z;
  const float o3 = (v.w - mean) * rs * g.w + b.w;
  u16x4 o;
  o.x = f2bf(o0); o.y = f2bf(o1); o.z = f2bf(o2); o.w = f2bf(o3);
  *(u16x4*)(hcat + (size_t)row * KCAT + 2048 + base) = o;
  xq[row * 256 + tid] = pack4_fp8(o0, o1, o2, o3);
}

// ---------------------------------------------------------------------------
// K2: f32 [K,N] -> bf16 [N,K] transpose (stitches two sources along K).
// ---------------------------------------------------------------------------
__global__ void cvt_transpose(const float* __restrict__ srcA,
                              const float* __restrict__ srcB,
                              int splitK, int K, int N,
                              u16* __restrict__ dst) {
  __shared__ float tile[32][33];
  const int n0 = blockIdx.x * 32, k0 = blockIdx.y * 32;
  const int tx = threadIdx.x, ty = threadIdx.y;
  for (int i = ty; i < 32; i += 8) {
    const int k = k0 + i;
    const float v = (k < splitK) ? srcA[(size_t)k * N + n0 + tx]
                                 : srcB[(size_t)(k - splitK) * N + n0 + tx];
    tile[i][tx] = v;
  }
  __syncthreads();
  for (int i = ty; i < 32; i += 8) {
    dst[(size_t)(n0 + i) * K + k0 + tx] = f2bf(tile[tx][i]);
  }
}

// ---------------------------------------------------------------------------
// K3b: exclusive prefix sum over 16384 counts (single block, 1024 thr).
// ---------------------------------------------------------------------------
__global__ __launch_bounds__(1024) void scan_kernel(const int* __restrict__ cnt,
                                                    int* __restrict__ off,
                                                    int* __restrict__ cursor) {
  __shared__ int partial[1024];
  const int tid  = threadIdx.x;
  const int base = tid * 16;
  int local[16];
  int s = 0;
#pragma unroll
  for (int i = 0; i < 16; ++i) { local[i] = s; s += cnt[base + i]; }
  partial[tid] = s;
  __syncthreads();
  for (int st = 1; st < 1024; st <<= 1) {
    const int v = (tid >= st) ? partial[tid - st] : 0;
    __syncthreads();
    partial[tid] += v;
    __syncthreads();
  }
  const int pre = (tid == 0) ? 0 : partial[tid - 1];
#pragma unroll
  for (int i = 0; i < 16; ++i) {
    const int o = pre + local[i];
    off[base + i]    = o;
    cursor[base + i] = o;
  }
}

// ---------------------------------------------------------------------------
// K3c: scatter edge SOURCE ids into buckets (4B per edge, not row data).
// ---------------------------------------------------------------------------
__global__ void fill_kernel(const int* __restrict__ edge_index,
                            const int* __restrict__ edge_type,
                            int* __restrict__ cursor,
                            int* __restrict__ bucket_src) {
  const int e = blockIdx.x * 256 + threadIdx.x;
  const int s = edge_index[e];
  const int d = edge_index[E_NUM + e];
  const int r = edge_type[e];
  const int pos = atomicAdd(&cursor[r * NNODE + d], 1);
  bucket_src[pos] = s;
}

// ---------------------------------------------------------------------------
// K4: wave-per-bucket aggregation. One 64-lane wave owns one (rel,node)
// bucket; lane covers 16 cols (dwordx4 of fp8). Edge ids held in a register
// and broadcast via __shfl — no LDS, no __syncthreads. 4 buckets/block.
// ---------------------------------------------------------------------------
__global__ __launch_bounds__(256) void aggregate_kernel(
    const int* __restrict__ cnt, const int* __restrict__ off,
    const int* __restrict__ bucket_src, const u32* __restrict__ xq,
    u16* __restrict__ hcat) {
  const int b    = blockIdx.x * 4 + (threadIdx.x >> 6);  // bucket id
  const int lane = threadIdx.x & 63;
  const int r    = b >> 13;
  const int node = b & (NNODE - 1);
  const int n     = cnt[b];
  const int start = off[b];

  float a[16] = {};

  for (int j0 = 0; j0 < n; j0 += 64) {
    const int m = min(n - j0, 64);
    const int myid = (lane < m) ? bucket_src[start + j0 + lane] : 0;
    int j = 0;
    for (; j + 3 < m; j += 4) {
      const int s0 = __shfl(myid, j,     64);
      const int s1 = __shfl(myid, j + 1, 64);
      const int s2 = __shfl(myid, j + 2, 64);
      const int s3 = __shfl(myid, j + 3, 64);
      const uint4 x0 = *(const uint4*)(xq + s0 * 256 + lane * 4);
      const uint4 x1 = *(const uint4*)(xq + s1 * 256 + lane * 4);
      const uint4 x2 = *(const uint4*)(xq + s2 * 256 + lane * 4);
      const uint4 x3 = *(const uint4*)(xq + s3 * 256 + lane * 4);
      acc16_fp8(a, x0); acc16_fp8(a, x1);
      acc16_fp8(a, x2); acc16_fp8(a, x3);
    }
    for (; j < m; ++j) {
      const int s0 = __shfl(myid, j, 64);
      const uint4 x0 = *(const uint4*)(xq + s0 * 256 + lane * 4);
      acc16_fp8(a, x0);
    }
  }

  const float inv = 1.0f / fmaxf((float)n, 1.0f);
  uint4 o0, o1;
  o0.x = (u32)f2bf(a[0] * inv)  | ((u32)f2bf(a[1] * inv)  << 16);
  o0.y = (u32)f2bf(a[2] * inv)  | ((u32)f2bf(a[3] * inv)  << 16);
  o0.z = (u32)f2bf(a[4] * inv)  | ((u32)f2bf(a[5] * inv)  << 16);
  o0.w = (u32)f2bf(a[6] * inv)  | ((u32)f2bf(a[7] * inv)  << 16);
  o1.x = (u32)f2bf(a[8] * inv)  | ((u32)f2bf(a[9] * inv)  << 16);
  o1.y = (u32)f2bf(a[10] * inv) | ((u32)f2bf(a[11] * inv) << 16);
  o1.z = (u32)f2bf(a[12] * inv) | ((u32)f2bf(a[13] * inv) << 16);
  o1.w = (u32)f2bf(a[14] * inv) | ((u32)f2bf(a[15] * inv) << 16);
  u16* dp = hcat + (size_t)node * KCAT + (size_t)r * DDIM + lane * 16;
  *(uint4*)(dp)     = o0;
  *(uint4*)(dp + 8) = o1;
}

// ---------------------------------------------------------------------------
// Shared 8-phase GEMM machinery (expanded in gemm kernels; names resolve to
// kernel-local variables at expansion site).
// R11: no forced lgkmcnt(0) — compiler inserts fine-grained lgkmcnt(N) per
// ds_read->MFMA dependency. FENCE (zero-cost asm memory clobber) after every
// s_barrier blocks cross-barrier load hoisting (cross-wave WAR guard).
// ---------------------------------------------------------------------------

#define MF16(a, b, c) __builtin_amdgcn_mfma_f32_16x16x32_bf16(a, b, c, 0, 0, 0)

#define FENCE asm volatile("" ::: "memory")

#define STAGE_A(t, p, b)                                                   \
  { GLD16(gA0 + (size_t)(t) * 64 + (size_t)(p) * KP,                       \
          &sA[b][(p) * 8192 + lofs0]);                                     \
    GLD16(gA1 + (size_t)(t) * 64 + (size_t)(p) * KP,                       \
          &sA[b][(p) * 8192 + lofs1]); }

#define STAGE_B(t, p, b)                                                   \
  { GLD16(gB0 + (size_t)(t) * 64 + (size_t)(p) * KP,                       \
          &sB[b][(p) * 8192 + lofs0]);                                     \
    GLD16(gB1 + (size_t)(t) * 64 + (size_t)(p) * KP,                       \
          &sB[b][(p) * 8192 + lofs1]); }

#define BVLOAD(b)                                                          \
  { const bf16x8* pB_ = (const bf16x8*)sB[b];                              \
    bv[0][0] = pB_[brow80 + sega0]; bv[0][1] = pB_[brow80 + sega1];        \
    bv[1][0] = pB_[brow81 + sega0]; bv[1][1] = pB_[brow81 + sega1];        \
    bv[2][0] = pB_[brow82 + sega0]; bv[2][1] = pB_[brow82 + sega1];        \
    bv[3][0] = pB_[brow83 + sega0]; bv[3][1] = pB_[brow83 + sega1]; }

#define NOWAIT ((void)0)
#define NOSTAGE ((void)0)
#define VM4 asm volatile("s_waitcnt vmcnt(4)" ::: "memory")
#define VM2 asm volatile("s_waitcnt vmcnt(2)" ::: "memory")
#define VM0 asm volatile("s_waitcnt vmcnt(0)" ::: "memory")

#define PHASE(Q, BUFI, STAGE, ENDW)                                        \
  { const bf16x8* pA_ = (const bf16x8*)sA[BUFI];                           \
    bf16x8 a00 = pA_[arow8[2 * (Q)] + sega0];                              \
    bf16x8 a01 = pA_[arow8[2 * (Q)] + sega1];                              \
    bf16x8 a10 = pA_[arow8[2 * (Q) + 1] + sega0];                          \
    bf16x8 a11 = pA_[arow8[2 * (Q) + 1] + sega1];                          \
    STAGE;                                                                 \
    __builtin_amdgcn_s_barrier();                                          \
    FENCE;                                                                 \
    __builtin_amdgcn_s_setprio(1);                                         \
    _Pragma("unroll")                                                      \
    for (int ni = 0; ni < 4; ++ni) {                                       \
      acc[2 * (Q)][ni]     = MF16(a00, bv[ni][0], acc[2 * (Q)][ni]);       \
      acc[2 * (Q)][ni]     = MF16(a01, bv[ni][1], acc[2 * (Q)][ni]);       \
      acc[2 * (Q) + 1][ni] = MF16(a10, bv[ni][0], acc[2 * (Q) + 1][ni]);   \
      acc[2 * (Q) + 1][ni] = MF16(a11, bv[ni][1], acc[2 * (Q) + 1][ni]);   \
    }                                                                      \
    __builtin_amdgcn_s_setprio(0);                                         \
    ENDW;                                                                  \
    __builtin_amdgcn_s_barrier();                                          \
    FENCE; }

// ---------------------------------------------------------------------------
// GEMM1: out1[8192x4096] = bf16(relu(hcat[8192x3072] @ WcatT^T + bias))
// 256x256 tile, BK=64, 512 thr / 8 waves (2Mx4N), 128 KiB dbuf LDS,
// 8-phase counted-vmcnt schedule; vmcnt(4) only at phases 4/8.
// R10 epilogue: bias+relu+f2bf -> LDS [128][264] u16 -> dwordx4 stores.
// ---------------------------------------------------------------------------
__global__ __launch_bounds__(512) void gemm1_kernel(
    const u16* __restrict__ A, const u16* __restrict__ Bt,
    const float* __restrict__ bias, u16* __restrict__ obf) {
  const int K = KCAT, N = FDIM;
  const int NT = K / 64;                    // 48 K-tiles
  const size_t KP = (size_t)128 * K;        // piece-1 global row offset
  __shared__ __align__(16) u16 smem[65536];   // 128 KB
  u16 (*sA)[16384] = (u16(*)[16384])(smem);          // 2 bufs x 256x64 bf16
  u16 (*sB)[16384] = (u16(*)[16384])(smem + 32768);  // 2 bufs x 256x64 bf16

  const int tid  = threadIdx.x;
  const int lane = tid & 63;
  const int wave = tid >> 6;
  const int wr = wave >> 2, wc = wave & 3;    // 2 x 4 wave grid
  const int lr = lane & 15, quad = lane >> 4;

  const int bid = blockIdx.x;
  const int swz = (bid & 7) * 64 + (bid >> 3);
  const int bm = (swz >> 4) * 256;
  const int bn = (swz & 15) * 256;

  int lofs0, lofs1;
  const u16 *gA0, *gA1, *gB0, *gB1;
  {
    const int s0 = tid,       r0 = s0 >> 3, g0 = (s0 & 7) ^ (r0 & 7);
    const int s1 = tid + 512, r1 = s1 >> 3, g1 = (s1 & 7) ^ (r1 & 7);
    gA0 = A  + (size_t)(bm + r0) * K + g0 * 8;
    gA1 = A  + (size_t)(bm + r1) * K + g1 * 8;
    gB0 = Bt + (size_t)(bn + r0) * K + g0 * 8;
    gB1 = Bt + (size_t)(bn + r1) * K + g1 * 8;
    lofs0 = s0 * 8; lofs1 = s1 * 8;
  }

  int arow8[8];
#pragma unroll
  for (int mi = 0; mi < 8; ++mi) arow8[mi] = (wr * 128 + mi * 16 + lr) * 8;
  const int brow80 = (wc * 64 +  0 + lr) * 8;
  const int brow81 = (wc * 64 + 16 + lr) * 8;
  const int brow82 = (wc * 64 + 32 + lr) * 8;
  const int brow83 = (wc * 64 + 48 + lr) * 8;
  const int sega0 = quad ^ (lr & 7);
  const int sega1 = (4 + quad) ^ (lr & 7);

  f32x4 acc[8][4] = {};
  bf16x8 bv[4][2];

  STAGE_B(0, 0, 0) STAGE_B(0, 1, 0)
  STAGE_A(0, 0, 0) STAGE_A(0, 1, 0)
  STAGE_B(1, 0, 1) STAGE_B(1, 1, 1)
  asm volatile("s_waitcnt vmcnt(4)" ::: "memory");
  __builtin_amdgcn_s_barrier();
  FENCE;

  for (int tt = 0; tt < NT - 2; tt += 2) {
    PHASE(0, 0, BVLOAD(0); STAGE_A(tt + 1, 0, 1), NOWAIT)
    PHASE(1, 0, STAGE_A(tt + 1, 1, 1), NOWAIT)
    PHASE(2, 0, STAGE_B(tt + 2, 0, 0), NOWAIT)
    PHASE(3, 0, STAGE_B(tt + 2, 1, 0), VM4)
    PHASE(0, 1, BVLOAD(1); STAGE_A(tt + 2, 0, 0), NOWAIT)
    PHASE(1, 1, STAGE_A(tt + 2, 1, 0), NOWAIT)
    PHASE(2, 1, STAGE_B(tt + 3, 0, 1), NOWAIT)
    PHASE(3, 1, STAGE_B(tt + 3, 1, 1), VM4)
  }
  PHASE(0, 0, BVLOAD(0); STAGE_A(NT - 1, 0, 1), NOWAIT)
  PHASE(1, 0, STAGE_A(NT - 1, 1, 1), NOWAIT)
  PHASE(2, 0, NOSTAGE, NOWAIT)
  PHASE(3, 0, NOSTAGE, VM0)
  PHASE(0, 1, BVLOAD(1), NOWAIT)
  PHASE(1, 1, NOSTAGE, NOWAIT)
  PHASE(2, 1, NOSTAGE, NOWAIT)
  PHASE(3, 1, NOSTAGE, NOWAIT)

  // --- epilogue: bias+relu+f2bf -> LDS [128][264] -> dwordx4 stores ---
  const int CPAD = 264;                       // 264*2B row pitch: 16B-aligned
#pragma unroll
  for (int h = 0; h < 2; ++h) {
    if (wr == h) {
#pragma unroll
      for (int mi = 0; mi < 8; ++mi) {
        const int lrow = mi * 16 + quad * 4;
#pragma unroll
        for (int ni = 0; ni < 4; ++ni) {
          const int col = wc * 64 + ni * 16 + lr;
          const float bb = bias[bn + col];
#pragma unroll
          for (int r = 0; r < 4; ++r) {
            const float v = acc[mi][ni][r] + bb;
            smem[(lrow + r) * CPAD + col] = f2bf(fmaxf(v, 0.0f));
          }
        }
      }
    }
    __syncthreads();
#pragma unroll
    for (int i = 0; i < 8; ++i) {
      const int chunk = tid + 512 * i;        // 4096 chunks of 16B
      const int row = chunk >> 5;             // 0..127
      const int seg = chunk & 31;             // 0..31
      const uint4 val = *(const uint4*)(smem + row * CPAD + seg * 8);
      *(uint4*)(obf + (size_t)(bm + h * 128 + row) * N + bn + seg * 8) = val;
    }
    __syncthreads();
  }
}

// ---------------------------------------------------------------------------
// GEMM2: out[8192x1024] = resid + out1[8192x4096] @ woT^T
// 256x128 tile, BK=64, 512 thr / 8 waves (4Mx2N, 64x64/wave), 96 KiB dbuf
// LDS, 2 phases/K-tile x 16 MFMA, counted VM2, grid 256 = 1/CU.
// R11 epilogue: acc -> LDS f32 [128][132] -> float4 resid-add + store,
// two row-half rounds (LDS dead post-loop; was 64B-coalesced scalar f32).
// ---------------------------------------------------------------------------
__global__ __launch_bounds__(512) void gemm2_kernel(
    const u16* __restrict__ A, const u16* __restrict__ Bt,
    const float* __restrict__ resid, float* __restrict__ out) {
  const int K = FDIM, N = DDIM;
  const int NT = K / 64;                    // 64 K-tiles
  const size_t KP = (size_t)128 * K;        // piece-1 global row offset
  __shared__ __align__(16) u16 smem[49152];   // 96 KB
  u16 (*sA)[16384] = (u16(*)[16384])(smem);          // 2 bufs x 256x64
  u16 (*sB)[8192]  = (u16(*)[8192])(smem + 32768);   // 2 bufs x 128x64

  const int tid  = threadIdx.x;
  const int lane = tid & 63;
  const int wave = tid >> 6;
  const int wr = wave >> 1, wc = wave & 1;    // 4 x 2 wave grid (64x64/wave)
  const int lr = lane & 15, quad = lane >> 4;

  const int bid = blockIdx.x;
  const int swz = (bid & 7) * 32 + (bid >> 3);
  const int bm = (swz >> 3) * 256;
  const int bn = (swz & 7) * 128;

  int lofs0, lofs1;
  const u16 *gA0, *gA1, *gB0, *gB1;
  {
    const int s0 = tid,       r0 = s0 >> 3, g0 = (s0 & 7) ^ (r0 & 7);
    const int s1 = tid + 512, r1 = s1 >> 3, g1 = (s1 & 7) ^ (r1 & 7);
    gA0 = A  + (size_t)(bm + r0) * K + g0 * 8;
    gA1 = A  + (size_t)(bm + r1) * K + g1 * 8;
    gB0 = Bt + (size_t)(bn + r0) * K + g0 * 8;   // B rows 0..63 (slot tid)
    gB1 = Bt + (size_t)(bn + r1) * K + g1 * 8;   // B rows 64..127 (tid+512)
    lofs0 = s0 * 8; lofs1 = s1 * 8;
  }

  int arow8[4];
#pragma unroll
  for (int mi = 0; mi < 4; ++mi) arow8[mi] = (wr * 64 + mi * 16 + lr) * 8;
  const int brow80 = (wc * 64 +  0 + lr) * 8;
  const int brow81 = (wc * 64 + 16 + lr) * 8;
  const int brow82 = (wc * 64 + 32 + lr) * 8;
  const int brow83 = (wc * 64 + 48 + lr) * 8;
  const int sega0 = quad ^ (lr & 7);
  const int sega1 = (4 + quad) ^ (lr & 7);

  f32x4 acc[4][4] = {};
  bf16x8 bv[4][2];

  STAGE_B(0, 0, 0)
  STAGE_A(0, 0, 0) STAGE_A(0, 1, 0)
  STAGE_B(1, 0, 1)
  asm volatile("s_waitcnt vmcnt(2)" ::: "memory");
  __builtin_amdgcn_s_barrier();
  FENCE;

  for (int tt = 0; tt < NT - 2; tt += 2) {
    PHASE(0, 0, BVLOAD(0); STAGE_A(tt + 1, 0, 1), NOWAIT)
    PHASE(1, 0, STAGE_A(tt + 1, 1, 1); STAGE_B(tt + 2, 0, 0), VM2)
    PHASE(0, 1, BVLOAD(1); STAGE_A(tt + 2, 0, 0), NOWAIT)
    PHASE(1, 1, STAGE_A(tt + 2, 1, 0); STAGE_B(tt + 3, 0, 1), VM2)
  }
  PHASE(0, 0, BVLOAD(0); STAGE_A(NT - 1, 0, 1), NOWAIT)
  PHASE(1, 0, STAGE_A(NT - 1, 1, 1), VM0)
  PHASE(0, 1, BVLOAD(1), NOWAIT)
  PHASE(1, 1, NOSTAGE, NOWAIT)

  // --- R11 epilogue: acc -> LDS f32 [128][132] -> float4 resid+store ---
  float* smemf = (float*)smem;
  const int FPAD = 132;                     // 132*4B pitch: 16B-aligned
#pragma unroll
  for (int h = 0; h < 2; ++h) {
    __syncthreads();
    if ((wr >> 1) == h) {
#pragma unroll
      for (int mi = 0; mi < 4; ++mi) {
        const int srow0 = (wr & 1) * 64 + mi * 16 + quad * 4;
#pragma unroll
        for (int ni = 0; ni < 4; ++ni) {
          const int scol = wc * 64 + ni * 16 + lr;
#pragma unroll
          for (int r = 0; r < 4; ++r)
            smemf[(srow0 + r) * FPAD + scol] = acc[mi][ni][r];
        }
      }
    }
    __syncthreads();
#pragma unroll
    for (int i = 0; i < 8; ++i) {
      const int chunk = tid + 512 * i;        // 4096 chunks of 16B
      const int row = chunk >> 5;             // 0..127
      const int seg = chunk & 31;             // 0..31
      const float4 lv = *(const float4*)(smemf + row * FPAD + seg * 4);
      const size_t gofs = (size_t)(bm + h * 128 + row) * N + bn + seg * 4;
      const float4 rv = *(const float4*)(resid + gofs);
      float4 ov;
      ov.x = rv.x + lv.x; ov.y = rv.y + lv.y;
      ov.z = rv.z + lv.z; ov.w = rv.w + lv.w;
      *(float4*)(out + gofs) = ov;
    }
  }
}

// ---------------------------------------------------------------------------
// Workspace layout (bytes):
//   hcat       [8192 x 3072] bf16              @ 0          (50331648)
//   WcatT      [4096 x 3072] bf16              @ 50331648   (25165824)
//   woT        [1024 x 4096] bf16              @ 75497472   ( 8388608)
//   out1       [8192 x 4096] bf16              @ 83886080   (67108864)
//     bucket_src [262144] i32 (aliases out1)   @ 83886080   ( 1048576)
//     cnt        [16384] i32                   @ 84934656   (   65536)
//     off        [16384] i32                   @ 85000192   (   65536)
//     cursor     [16384] i32                   @ 85065728   (   65536)
//     xq         [8192 x 1024] fp8             @ 85131264   ( 8388608)
//   (all aliased scratch consumed before GEMM1 writes out1)
// total: 150994944 bytes (144 MB)
// ---------------------------------------------------------------------------
extern "C" void kernel_launch(void* const* d_in, const int* in_sizes, int n_in,
                              void* d_out, int out_size, void* d_ws, size_t ws_size,
                              hipStream_t stream) {
  const float* hs     = (const float*)d_in[0];
  const float* weight = (const float*)d_in[1];   // [2,1024,4096]
  const float* root   = (const float*)d_in[2];   // [1024,4096]
  const float* bias   = (const float*)d_in[3];   // [4096]
  const float* wo     = (const float*)d_in[4];   // [4096,1024]
  const float* gamma  = (const float*)d_in[5];
  const float* beta   = (const float*)d_in[6];
  const int* edge_index = (const int*)d_in[7];   // [2,E]
  const int* edge_type  = (const int*)d_in[8];   // [E]
  float* out = (float*)d_out;

  char* ws = (char*)d_ws;
  u16*   hcat       = (u16*)(ws + 0);
  u16*   WcatT      = (u16*)(ws + 50331648);
  u16*   woT        = (u16*)(ws + 75497472);
  u16*   out1       = (u16*)(ws + 83886080);
  int*   bucket_src = (int*)(ws + 83886080);     // aliases out1 (consumed pre-GEMM1)
  int*   cnt        = (int*)(ws + 84934656);
  int*   off        = (int*)(ws + 85000192);
  int*   cursor     = (int*)(ws + 85065728);
  u32*   xq         = (u32*)(ws + 85131264);     // fp8 x, dense [8192][1024]

  (void)hipMemsetAsync(cnt, 0, 65536, stream);

  // LN + fused edge count
  ln_kernel<<<NNODE, 256, 0, stream>>>(hs, gamma, beta, hcat, xq,
                                       edge_index, edge_type, cnt);

  scan_kernel<<<1, 1024, 0, stream>>>(cnt, off, cursor);
  fill_kernel<<<E_NUM / 256, 256, 0, stream>>>(edge_index, edge_type, cursor, bucket_src);
  aggregate_kernel<<<NBKT / 4, 256, 0, stream>>>(cnt, off, bucket_src, xq, hcat);

  // weight transposes after aggregate: keeps xq L2-warm for the gather above
  cvt_transpose<<<dim3(FDIM / 32, KCAT / 32), dim3(32, 8), 0, stream>>>(
      weight, root, 2048, KCAT, FDIM, WcatT);
  cvt_transpose<<<dim3(DDIM / 32, FDIM / 32), dim3(32, 8), 0, stream>>>(
      wo, wo, FDIM, FDIM, DDIM, woT);

  // out1 = relu([h0|h1|x] @ [W0;W1;root] + bias)   [8192 x 4096] bf16
  gemm1_kernel<<<512, 512, 0, stream>>>(hcat, WcatT, bias, out1);

  // out = hs + out1 @ wo                            [8192 x 1024] f32
  gemm2_kernel<<<256, 512, 0, stream>>>(out1, woT, hs, out);
}

// Round 8
// 452.832 us; speedup vs baseline: 1.0673x; 1.0141x over previous
//
#include <hip/hip_runtime.h>

// ---------------------------------------------------------------------------
// T5GNNAdapt: LN -> RGCN scatter-mean (2 relations) -> [h0|h1|x] @ [W0;W1;root]
//             + bias -> relu -> @wo -> + residual
// Shapes: B=8,S=1024,D=1024,F=4096,E=262144,N=B*S=8192, K_cat=3072
// R7:  gemm1 -> 256^2 8-phase counted-vmcnt template.
// R8:  gemm2 -> same template (256x128, 2 phases/K-tile, VM2).
// R9:  FAILED gemm1 A-prefetch restructure (reverted). aggregate wave/bucket.
// R10: gemm1 LDS epilogue; count fused into ln.
// R11: lgkmcnt(0) drain removed + FENCE; gemm2 LDS epilogue. 459us.
// R12: (a) cvt_transposes fused into aggregate launch (HBM vs L3 overlap,
//      2 fewer dispatches). (b) aggregate: readlane broadcast, 1-batch-ahead
//      pipeline, f32x2 pk adds. [resubmit 2: cvt_pk_f32_fp8 'hi' operand
//      must be an immediate -> template<bool HI> cvt2_fp8]
// ---------------------------------------------------------------------------

typedef unsigned short u16;
typedef unsigned int   u32;
typedef __attribute__((ext_vector_type(8))) short bf16x8;
typedef __attribute__((ext_vector_type(4))) float f32x4;
typedef __attribute__((ext_vector_type(2))) float f32x2;

#define E_NUM  262144
#define NNODE  8192
#define NBKT   (2 * NNODE)      // 16384 (rel,dst) buckets
#define DDIM   1024
#define FDIM   4096
#define KCAT   3072
#define LN_EPS 1e-6f

#define AGG_BLOCKS  (NBKT / 4)                     // 4096
#define CVT1_BLOCKS ((FDIM / 32) * (KCAT / 32))    // 12288
#define CVT2_BLOCKS ((DDIM / 32) * (FDIM / 32))    // 4096

struct alignas(8) u16x4 { u16 x, y, z, w; };

__device__ __forceinline__ u16 f2bf(float f) {
  u32 u = __float_as_uint(f);
  u32 r = u + 0x7fffu + ((u >> 16) & 1u);   // RNE
  return (u16)(r >> 16);
}
__device__ __forceinline__ float bf2f(u16 h) {
  return __uint_as_float(((u32)h) << 16);
}

// ---- fp8 e4m3fn (OCP) encode/decode; HW cvt when available ---------------
__device__ __forceinline__ u32 enc_fp8_1(float f) {
  u32 u = __float_as_uint(f);
  u32 s = u >> 31;
  u32 mag = u & 0x7fffffffu;
  mag = mag + 0x7ffffu + ((mag >> 20) & 1u);          // RNE to 3 mant bits
  if (mag > 0x43e00000u) mag = 0x43e00000u;           // clamp to 448
  u32 e = mag >> 23;
  return (e <= 120u) ? 0u
                     : ((s << 7) | ((e - 120u) << 3) | ((mag >> 20) & 7u));
}

__device__ __forceinline__ u32 pack4_fp8(float a, float b, float c, float d) {
#if __has_builtin(__builtin_amdgcn_cvt_pk_fp8_f32)
  int v = 0;
  v = __builtin_amdgcn_cvt_pk_fp8_f32(a, b, v, false);  // bytes 0,1
  v = __builtin_amdgcn_cvt_pk_fp8_f32(c, d, v, true);   // bytes 2,3
  return (u32)v;
#else
  return enc_fp8_1(a) | (enc_fp8_1(b) << 8) | (enc_fp8_1(c) << 16) |
         (enc_fp8_1(d) << 24);
#endif
}

__device__ __forceinline__ float dec_fp8_1(u32 b) {
  u32 e = (b >> 3) & 15u;
  u32 f = ((b & 0x80u) << 24) | ((e + 120u) << 23) | ((b & 7u) << 20);
  return e ? __uint_as_float(f) : 0.0f;
}

template <bool HI>
__device__ __forceinline__ f32x2 cvt2_fp8(u32 q) {
#if __has_builtin(__builtin_amdgcn_cvt_pk_f32_fp8)
  return __builtin_amdgcn_cvt_pk_f32_fp8((int)q, HI);   // HI is an immediate
#else
  f32x2 r;
  const u32 sh = HI ? 16u : 0u;
  r.x = dec_fp8_1((q >> sh) & 0xffu);
  r.y = dec_fp8_1((q >> (sh + 8)) & 0xffu);
  return r;
#endif
}

// accumulate one dwordx4 (16 fp8) into 8 f32x2 accumulators (pk adds)
__device__ __forceinline__ void acc16q(f32x2* ac, uint4 q) {
  ac[0] += cvt2_fp8<false>(q.x); ac[1] += cvt2_fp8<true>(q.x);
  ac[2] += cvt2_fp8<false>(q.y); ac[3] += cvt2_fp8<true>(q.y);
  ac[4] += cvt2_fp8<false>(q.z); ac[5] += cvt2_fp8<true>(q.z);
  ac[6] += cvt2_fp8<false>(q.w); ac[7] += cvt2_fp8<true>(q.w);
}

// 16-byte global -> LDS async copy (wave-uniform LDS base + lane*16 layout)
#define GLD16(gp, lp)                                              \
  __builtin_amdgcn_global_load_lds(                                \
      (__attribute__((address_space(1))) u32*)(gp),                \
      (__attribute__((address_space(3))) u32*)(lp), 16, 0, 0)

// ---------------------------------------------------------------------------
// K1: LayerNorm (one-pass) + fused edge-count. Writes bf16 x into
// hcat[:, 2048:3072] AND fp8 copy into dense xq[8192x1024]. Lanes 0-31 of
// each block also count 32 edges into cnt.
// ---------------------------------------------------------------------------
__global__ void ln_kernel(const float* __restrict__ hs,
                          const float* __restrict__ gamma,
                          const float* __restrict__ beta,
                          u16* __restrict__ hcat,
                          u32* __restrict__ xq,
                          const int* __restrict__ edge_index,
                          const int* __restrict__ edge_type,
                          int* __restrict__ cnt) {
  const int row = blockIdx.x;
  const int tid = threadIdx.x;
  const float4 v = ((const float4*)(hs + (size_t)row * DDIM))[tid];

  if (tid < 32) {                       // fused count: 32 edges per block
    const int e = (row << 5) + tid;
    const int d = edge_index[E_NUM + e];
    const int r = edge_type[e];
    atomicAdd(&cnt[r * NNODE + d], 1);
  }

  __shared__ float r1[256], r2[256];
  r1[tid] = v.x + v.y + v.z + v.w;
  r2[tid] = v.x * v.x + v.y * v.y + v.z * v.z + v.w * v.w;
  __syncthreads();
  for (int st = 128; st > 0; st >>= 1) {
    if (tid < st) { r1[tid] += r1[tid + st]; r2[tid] += r2[tid + st]; }
    __syncthreads();
  }
  const float mean = r1[0] * (1.0f / DDIM);
  const float var  = r2[0] * (1.0f / DDIM) - mean * mean;
  const float rs   = rsqrtf(var + LN_EPS);

  const int base = tid * 4;
  const float4 g = *(const float4*)(gamma + base);
  const float4 b = *(const float4*)(beta + base);
  const float o0 = (v.x - mean) * rs * g.x + b.x;
  const float o1 = (v.y - mean) * rs * g.y + b.y;
  const float o2 = (v.z - mean) * rs * g.z + b.z;
  const float o3 = (v.w - mean) * rs * g.w + b.w;
  u16x4 o;
  o.x = f2bf(o0); o.y = f2bf(o1); o.z = f2bf(o2); o.w = f2bf(o3);
  *(u16x4*)(hcat + (size_t)row * KCAT + 2048 + base) = o;
  xq[row * 256 + tid] = pack4_fp8(o0, o1, o2, o3);
}

// ---------------------------------------------------------------------------
// K3b: exclusive prefix sum over 16384 counts (single block, 1024 thr).
// ---------------------------------------------------------------------------
__global__ __launch_bounds__(1024) void scan_kernel(const int* __restrict__ cnt,
                                                    int* __restrict__ off,
                                                    int* __restrict__ cursor) {
  __shared__ int partial[1024];
  const int tid  = threadIdx.x;
  const int base = tid * 16;
  int local[16];
  int s = 0;
#pragma unroll
  for (int i = 0; i < 16; ++i) { local[i] = s; s += cnt[base + i]; }
  partial[tid] = s;
  __syncthreads();
  for (int st = 1; st < 1024; st <<= 1) {
    const int v = (tid >= st) ? partial[tid - st] : 0;
    __syncthreads();
    partial[tid] += v;
    __syncthreads();
  }
  const int pre = (tid == 0) ? 0 : partial[tid - 1];
#pragma unroll
  for (int i = 0; i < 16; ++i) {
    const int o = pre + local[i];
    off[base + i]    = o;
    cursor[base + i] = o;
  }
}

// ---------------------------------------------------------------------------
// K3c: scatter edge SOURCE ids into buckets (4B per edge, not row data).
// ---------------------------------------------------------------------------
__global__ void fill_kernel(const int* __restrict__ edge_index,
                            const int* __restrict__ edge_type,
                            int* __restrict__ cursor,
                            int* __restrict__ bucket_src) {
  const int e = blockIdx.x * 256 + threadIdx.x;
  const int s = edge_index[e];
  const int d = edge_index[E_NUM + e];
  const int r = edge_type[e];
  const int pos = atomicAdd(&cursor[r * NNODE + d], 1);
  bucket_src[pos] = s;
}

// ---------------------------------------------------------------------------
// K4 (R12): fused aggregate + weight transposes.
// Blocks [0, 4096): wave-per-bucket fp8 gather-mean (L3-bound).
//   readlane broadcast (SALU), 1-batch-ahead pipeline, f32x2 pk adds.
// Blocks [4096, 16384): WcatT transpose (HBM-bound — overlaps gather).
// Blocks [16384, 20480): woT transpose.
// ---------------------------------------------------------------------------
__device__ __forceinline__ void cvt_body(const float* __restrict__ srcA,
                                         const float* __restrict__ srcB,
                                         int splitK, int K, int N,
                                         u16* __restrict__ dst,
                                         int n0, int k0, int tx, int ty,
                                         float (*tile)[33]) {
  for (int i = ty; i < 32; i += 8) {
    const int k = k0 + i;
    const float v = (k < splitK) ? srcA[(size_t)k * N + n0 + tx]
                                 : srcB[(size_t)(k - splitK) * N + n0 + tx];
    tile[i][tx] = v;
  }
  __syncthreads();
  for (int i = ty; i < 32; i += 8) {
    dst[(size_t)(n0 + i) * K + k0 + tx] = f2bf(tile[tx][i]);
  }
}

__global__ __launch_bounds__(256) void agg_cvt_kernel(
    const int* __restrict__ cnt, const int* __restrict__ off,
    const int* __restrict__ bucket_src, const u32* __restrict__ xq,
    u16* __restrict__ hcat,
    const float* __restrict__ weight, const float* __restrict__ root,
    u16* __restrict__ WcatT,
    const float* __restrict__ wo, u16* __restrict__ woT) {
  __shared__ float tile[32][33];
  const int bx  = blockIdx.x;
  const int tid = threadIdx.x;

  if (bx >= AGG_BLOCKS) {
    const int tx = tid & 31, ty = tid >> 5;
    if (bx < AGG_BLOCKS + CVT1_BLOCKS) {
      const int idx = bx - AGG_BLOCKS;
      cvt_body(weight, root, 2048, KCAT, FDIM, WcatT,
               (idx & 127) * 32, (idx >> 7) * 32, tx, ty, tile);
    } else {
      const int idx = bx - AGG_BLOCKS - CVT1_BLOCKS;
      cvt_body(wo, wo, FDIM, FDIM, DDIM, woT,
               (idx & 31) * 32, (idx >> 5) * 32, tx, ty, tile);
    }
    return;
  }

  // ---- aggregate path ----
  const int b    = bx * 4 + (tid >> 6);   // bucket id
  const int lane = tid & 63;
  const int r    = b >> 13;
  const int node = b & (NNODE - 1);
  const int n     = cnt[b];
  const int start = off[b];

  f32x2 ac[8] = {};

#define LDROW(j) (*(const uint4*)(xq +                                     \
    (size_t)__builtin_amdgcn_readlane(myid, (j)) * 256 + lane * 4))

  for (int j0 = 0; j0 < n; j0 += 64) {
    const int m = min(n - j0, 64);
    const int myid = (lane < m) ? bucket_src[start + j0 + lane] : 0;
    const int nb = m & ~3;
    if (nb) {
      uint4 c0 = LDROW(0), c1 = LDROW(1), c2 = LDROW(2), c3 = LDROW(3);
      for (int j = 4; j < nb; j += 4) {
        const uint4 t0 = LDROW(j),     t1 = LDROW(j + 1);
        const uint4 t2 = LDROW(j + 2), t3 = LDROW(j + 3);
        acc16q(ac, c0); acc16q(ac, c1); acc16q(ac, c2); acc16q(ac, c3);
        c0 = t0; c1 = t1; c2 = t2; c3 = t3;
      }
      acc16q(ac, c0); acc16q(ac, c1); acc16q(ac, c2); acc16q(ac, c3);
    }
    for (int j = nb; j < m; ++j) {
      const uint4 x0 = LDROW(j);
      acc16q(ac, x0);
    }
  }
#undef LDROW

  const float inv = 1.0f / fmaxf((float)n, 1.0f);
  uint4 o0, o1;
  o0.x = (u32)f2bf(ac[0].x * inv) | ((u32)f2bf(ac[0].y * inv) << 16);
  o0.y = (u32)f2bf(ac[1].x * inv) | ((u32)f2bf(ac[1].y * inv) << 16);
  o0.z = (u32)f2bf(ac[2].x * inv) | ((u32)f2bf(ac[2].y * inv) << 16);
  o0.w = (u32)f2bf(ac[3].x * inv) | ((u32)f2bf(ac[3].y * inv) << 16);
  o1.x = (u32)f2bf(ac[4].x * inv) | ((u32)f2bf(ac[4].y * inv) << 16);
  o1.y = (u32)f2bf(ac[5].x * inv) | ((u32)f2bf(ac[5].y * inv) << 16);
  o1.z = (u32)f2bf(ac[6].x * inv) | ((u32)f2bf(ac[6].y * inv) << 16);
  o1.w = (u32)f2bf(ac[7].x * inv) | ((u32)f2bf(ac[7].y * inv) << 16);
  u16* dp = hcat + (size_t)node * KCAT + (size_t)r * DDIM + lane * 16;
  *(uint4*)(dp)     = o0;
  *(uint4*)(dp + 8) = o1;
}

// ---------------------------------------------------------------------------
// Shared 8-phase GEMM machinery (expanded in gemm kernels; names resolve to
// kernel-local variables at expansion site).
// R11: no forced lgkmcnt(0) — compiler inserts fine-grained lgkmcnt(N) per
// ds_read->MFMA dependency. FENCE (zero-cost asm memory clobber) after every
// s_barrier blocks cross-barrier load hoisting (cross-wave WAR guard).
// ---------------------------------------------------------------------------

#define MF16(a, b, c) __builtin_amdgcn_mfma_f32_16x16x32_bf16(a, b, c, 0, 0, 0)

#define FENCE asm volatile("" ::: "memory")

#define STAGE_A(t, p, b)                                                   \
  { GLD16(gA0 + (size_t)(t) * 64 + (size_t)(p) * KP,                       \
          &sA[b][(p) * 8192 + lofs0]);                                     \
    GLD16(gA1 + (size_t)(t) * 64 + (size_t)(p) * KP,                       \
          &sA[b][(p) * 8192 + lofs1]); }

#define STAGE_B(t, p, b)                                                   \
  { GLD16(gB0 + (size_t)(t) * 64 + (size_t)(p) * KP,                       \
          &sB[b][(p) * 8192 + lofs0]);                                     \
    GLD16(gB1 + (size_t)(t) * 64 + (size_t)(p) * KP,                       \
          &sB[b][(p) * 8192 + lofs1]); }

#define BVLOAD(b)                                                          \
  { const bf16x8* pB_ = (const bf16x8*)sB[b];                              \
    bv[0][0] = pB_[brow80 + sega0]; bv[0][1] = pB_[brow80 + sega1];        \
    bv[1][0] = pB_[brow81 + sega0]; bv[1][1] = pB_[brow81 + sega1];        \
    bv[2][0] = pB_[brow82 + sega0]; bv[2][1] = pB_[brow82 + sega1];        \
    bv[3][0] = pB_[brow83 + sega0]; bv[3][1] = pB_[brow83 + sega1]; }

#define NOWAIT ((void)0)
#define NOSTAGE ((void)0)
#define VM4 asm volatile("s_waitcnt vmcnt(4)" ::: "memory")
#define VM2 asm volatile("s_waitcnt vmcnt(2)" ::: "memory")
#define VM0 asm volatile("s_waitcnt vmcnt(0)" ::: "memory")

#define PHASE(Q, BUFI, STAGE, ENDW)                                        \
  { const bf16x8* pA_ = (const bf16x8*)sA[BUFI];                           \
    bf16x8 a00 = pA_[arow8[2 * (Q)] + sega0];                              \
    bf16x8 a01 = pA_[arow8[2 * (Q)] + sega1];                              \
    bf16x8 a10 = pA_[arow8[2 * (Q) + 1] + sega0];                          \
    bf16x8 a11 = pA_[arow8[2 * (Q) + 1] + sega1];                          \
    STAGE;                                                                 \
    __builtin_amdgcn_s_barrier();                                          \
    FENCE;                                                                 \
    __builtin_amdgcn_s_setprio(1);                                         \
    _Pragma("unroll")                                                      \
    for (int ni = 0; ni < 4; ++ni) {                                       \
      acc[2 * (Q)][ni]     = MF16(a00, bv[ni][0], acc[2 * (Q)][ni]);       \
      acc[2 * (Q)][ni]     = MF16(a01, bv[ni][1], acc[2 * (Q)][ni]);       \
      acc[2 * (Q) + 1][ni] = MF16(a10, bv[ni][0], acc[2 * (Q) + 1][ni]);   \
      acc[2 * (Q) + 1][ni] = MF16(a11, bv[ni][1], acc[2 * (Q) + 1][ni]);   \
    }                                                                      \
    __builtin_amdgcn_s_setprio(0);                                         \
    ENDW;                                                                  \
    __builtin_amdgcn_s_barrier();                                          \
    FENCE; }

// ---------------------------------------------------------------------------
// GEMM1: out1[8192x4096] = bf16(relu(hcat[8192x3072] @ WcatT^T + bias))
// 256x256 tile, BK=64, 512 thr / 8 waves (2Mx4N), 128 KiB dbuf LDS,
// 8-phase counted-vmcnt schedule; vmcnt(4) only at phases 4/8.
// Epilogue: bias+relu+f2bf -> LDS [128][264] u16 -> dwordx4 stores.
// ---------------------------------------------------------------------------
__global__ __launch_bounds__(512) void gemm1_kernel(
    const u16* __restrict__ A, const u16* __restrict__ Bt,
    const float* __restrict__ bias, u16* __restrict__ obf) {
  const int K = KCAT, N = FDIM;
  const int NT = K / 64;                    // 48 K-tiles
  const size_t KP = (size_t)128 * K;        // piece-1 global row offset
  __shared__ __align__(16) u16 smem[65536];   // 128 KB
  u16 (*sA)[16384] = (u16(*)[16384])(smem);          // 2 bufs x 256x64 bf16
  u16 (*sB)[16384] = (u16(*)[16384])(smem + 32768);  // 2 bufs x 256x64 bf16

  const int tid  = threadIdx.x;
  const int lane = tid & 63;
  const int wave = tid >> 6;
  const int wr = wave >> 2, wc = wave & 3;    // 2 x 4 wave grid
  const int lr = lane & 15, quad = lane >> 4;

  const int bid = blockIdx.x;
  const int swz = (bid & 7) * 64 + (bid >> 3);
  const int bm = (swz >> 4) * 256;
  const int bn = (swz & 15) * 256;

  int lofs0, lofs1;
  const u16 *gA0, *gA1, *gB0, *gB1;
  {
    const int s0 = tid,       r0 = s0 >> 3, g0 = (s0 & 7) ^ (r0 & 7);
    const int s1 = tid + 512, r1 = s1 >> 3, g1 = (s1 & 7) ^ (r1 & 7);
    gA0 = A  + (size_t)(bm + r0) * K + g0 * 8;
    gA1 = A  + (size_t)(bm + r1) * K + g1 * 8;
    gB0 = Bt + (size_t)(bn + r0) * K + g0 * 8;
    gB1 = Bt + (size_t)(bn + r1) * K + g1 * 8;
    lofs0 = s0 * 8; lofs1 = s1 * 8;
  }

  int arow8[8];
#pragma unroll
  for (int mi = 0; mi < 8; ++mi) arow8[mi] = (wr * 128 + mi * 16 + lr) * 8;
  const int brow80 = (wc * 64 +  0 + lr) * 8;
  const int brow81 = (wc * 64 + 16 + lr) * 8;
  const int brow82 = (wc * 64 + 32 + lr) * 8;
  const int brow83 = (wc * 64 + 48 + lr) * 8;
  const int sega0 = quad ^ (lr & 7);
  const int sega1 = (4 + quad) ^ (lr & 7);

  f32x4 acc[8][4] = {};
  bf16x8 bv[4][2];

  STAGE_B(0, 0, 0) STAGE_B(0, 1, 0)
  STAGE_A(0, 0, 0) STAGE_A(0, 1, 0)
  STAGE_B(1, 0, 1) STAGE_B(1, 1, 1)
  asm volatile("s_waitcnt vmcnt(4)" ::: "memory");
  __builtin_amdgcn_s_barrier();
  FENCE;

  for (int tt = 0; tt < NT - 2; tt += 2) {
    PHASE(0, 0, BVLOAD(0); STAGE_A(tt + 1, 0, 1), NOWAIT)
    PHASE(1, 0, STAGE_A(tt + 1, 1, 1), NOWAIT)
    PHASE(2, 0, STAGE_B(tt + 2, 0, 0), NOWAIT)
    PHASE(3, 0, STAGE_B(tt + 2, 1, 0), VM4)
    PHASE(0, 1, BVLOAD(1); STAGE_A(tt + 2, 0, 0), NOWAIT)
    PHASE(1, 1, STAGE_A(tt + 2, 1, 0), NOWAIT)
    PHASE(2, 1, STAGE_B(tt + 3, 0, 1), NOWAIT)
    PHASE(3, 1, STAGE_B(tt + 3, 1, 1), VM4)
  }
  PHASE(0, 0, BVLOAD(0); STAGE_A(NT - 1, 0, 1), NOWAIT)
  PHASE(1, 0, STAGE_A(NT - 1, 1, 1), NOWAIT)
  PHASE(2, 0, NOSTAGE, NOWAIT)
  PHASE(3, 0, NOSTAGE, VM0)
  PHASE(0, 1, BVLOAD(1), NOWAIT)
  PHASE(1, 1, NOSTAGE, NOWAIT)
  PHASE(2, 1, NOSTAGE, NOWAIT)
  PHASE(3, 1, NOSTAGE, NOWAIT)

  // --- epilogue: bias+relu+f2bf -> LDS [128][264] -> dwordx4 stores ---
  const int CPAD = 264;                       // 264*2B row pitch: 16B-aligned
#pragma unroll
  for (int h = 0; h < 2; ++h) {
    if (wr == h) {
#pragma unroll
      for (int mi = 0; mi < 8; ++mi) {
        const int lrow = mi * 16 + quad * 4;
#pragma unroll
        for (int ni = 0; ni < 4; ++ni) {
          const int col = wc * 64 + ni * 16 + lr;
          const float bb = bias[bn + col];
#pragma unroll
          for (int r = 0; r < 4; ++r) {
            const float v = acc[mi][ni][r] + bb;
            smem[(lrow + r) * CPAD + col] = f2bf(fmaxf(v, 0.0f));
          }
        }
      }
    }
    __syncthreads();
#pragma unroll
    for (int i = 0; i < 8; ++i) {
      const int chunk = tid + 512 * i;        // 4096 chunks of 16B
      const int row = chunk >> 5;             // 0..127
      const int seg = chunk & 31;             // 0..31
      const uint4 val = *(const uint4*)(smem + row * CPAD + seg * 8);
      *(uint4*)(obf + (size_t)(bm + h * 128 + row) * N + bn + seg * 8) = val;
    }
    __syncthreads();
  }
}

// ---------------------------------------------------------------------------
// GEMM2: out[8192x1024] = resid + out1[8192x4096] @ woT^T
// 256x128 tile, BK=64, 512 thr / 8 waves (4Mx2N, 64x64/wave), 96 KiB dbuf
// LDS, 2 phases/K-tile x 16 MFMA, counted VM2, grid 256 = 1/CU.
// Epilogue: acc -> LDS f32 [128][132] -> float4 resid-add + store.
// ---------------------------------------------------------------------------
__global__ __launch_bounds__(512) void gemm2_kernel(
    const u16* __restrict__ A, const u16* __restrict__ Bt,
    const float* __restrict__ resid, float* __restrict__ out) {
  const int K = FDIM, N = DDIM;
  const int NT = K / 64;                    // 64 K-tiles
  const size_t KP = (size_t)128 * K;        // piece-1 global row offset
  __shared__ __align__(16) u16 smem[49152];   // 96 KB
  u16 (*sA)[16384] = (u16(*)[16384])(smem);          // 2 bufs x 256x64
  u16 (*sB)[8192]  = (u16(*)[8192])(smem + 32768);   // 2 bufs x 128x64

  const int tid  = threadIdx.x;
  const int lane = tid & 63;
  const int wave = tid >> 6;
  const int wr = wave >> 1, wc = wave & 1;    // 4 x 2 wave grid (64x64/wave)
  const int lr = lane & 15, quad = lane >> 4;

  const int bid = blockIdx.x;
  const int swz = (bid & 7) * 32 + (bid >> 3);
  const int bm = (swz >> 3) * 256;
  const int bn = (swz & 7) * 128;

  int lofs0, lofs1;
  const u16 *gA0, *gA1, *gB0, *gB1;
  {
    const int s0 = tid,       r0 = s0 >> 3, g0 = (s0 & 7) ^ (r0 & 7);
    const int s1 = tid + 512, r1 = s1 >> 3, g1 = (s1 & 7) ^ (r1 & 7);
    gA0 = A  + (size_t)(bm + r0) * K + g0 * 8;
    gA1 = A  + (size_t)(bm + r1) * K + g1 * 8;
    gB0 = Bt + (size_t)(bn + r0) * K + g0 * 8;   // B rows 0..63 (slot tid)
    gB1 = Bt + (size_t)(bn + r1) * K + g1 * 8;   // B rows 64..127 (tid+512)
    lofs0 = s0 * 8; lofs1 = s1 * 8;
  }

  int arow8[4];
#pragma unroll
  for (int mi = 0; mi < 4; ++mi) arow8[mi] = (wr * 64 + mi * 16 + lr) * 8;
  const int brow80 = (wc * 64 +  0 + lr) * 8;
  const int brow81 = (wc * 64 + 16 + lr) * 8;
  const int brow82 = (wc * 64 + 32 + lr) * 8;
  const int brow83 = (wc * 64 + 48 + lr) * 8;
  const int sega0 = quad ^ (lr & 7);
  const int sega1 = (4 + quad) ^ (lr & 7);

  f32x4 acc[4][4] = {};
  bf16x8 bv[4][2];

  STAGE_B(0, 0, 0)
  STAGE_A(0, 0, 0) STAGE_A(0, 1, 0)
  STAGE_B(1, 0, 1)
  asm volatile("s_waitcnt vmcnt(2)" ::: "memory");
  __builtin_amdgcn_s_barrier();
  FENCE;

  for (int tt = 0; tt < NT - 2; tt += 2) {
    PHASE(0, 0, BVLOAD(0); STAGE_A(tt + 1, 0, 1), NOWAIT)
    PHASE(1, 0, STAGE_A(tt + 1, 1, 1); STAGE_B(tt + 2, 0, 0), VM2)
    PHASE(0, 1, BVLOAD(1); STAGE_A(tt + 2, 0, 0), NOWAIT)
    PHASE(1, 1, STAGE_A(tt + 2, 1, 0); STAGE_B(tt + 3, 0, 1), VM2)
  }
  PHASE(0, 0, BVLOAD(0); STAGE_A(NT - 1, 0, 1), NOWAIT)
  PHASE(1, 0, STAGE_A(NT - 1, 1, 1), VM0)
  PHASE(0, 1, BVLOAD(1), NOWAIT)
  PHASE(1, 1, NOSTAGE, NOWAIT)

  // --- epilogue: acc -> LDS f32 [128][132] -> float4 resid+store ---
  float* smemf = (float*)smem;
  const int FPAD = 132;                     // 132*4B pitch: 16B-aligned
#pragma unroll
  for (int h = 0; h < 2; ++h) {
    __syncthreads();
    if ((wr >> 1) == h) {
#pragma unroll
      for (int mi = 0; mi < 4; ++mi) {
        const int srow0 = (wr & 1) * 64 + mi * 16 + quad * 4;
#pragma unroll
        for (int ni = 0; ni < 4; ++ni) {
          const int scol = wc * 64 + ni * 16 + lr;
#pragma unroll
          for (int r = 0; r < 4; ++r)
            smemf[(srow0 + r) * FPAD + scol] = acc[mi][ni][r];
        }
      }
    }
    __syncthreads();
#pragma unroll
    for (int i = 0; i < 8; ++i) {
      const int chunk = tid + 512 * i;        // 4096 chunks of 16B
      const int row = chunk >> 5;             // 0..127
      const int seg = chunk & 31;             // 0..31
      const float4 lv = *(const float4*)(smemf + row * FPAD + seg * 4);
      const size_t gofs = (size_t)(bm + h * 128 + row) * N + bn + seg * 4;
      const float4 rv = *(const float4*)(resid + gofs);
      float4 ov;
      ov.x = rv.x + lv.x; ov.y = rv.y + lv.y;
      ov.z = rv.z + lv.z; ov.w = rv.w + lv.w;
      *(float4*)(out + gofs) = ov;
    }
  }
}

// ---------------------------------------------------------------------------
// Workspace layout (bytes):
//   hcat       [8192 x 3072] bf16              @ 0          (50331648)
//   WcatT      [4096 x 3072] bf16              @ 50331648   (25165824)
//   woT        [1024 x 4096] bf16              @ 75497472   ( 8388608)
//   out1       [8192 x 4096] bf16              @ 83886080   (67108864)
//     bucket_src [262144] i32 (aliases out1)   @ 83886080   ( 1048576)
//     cnt        [16384] i32                   @ 84934656   (   65536)
//     off        [16384] i32                   @ 85000192   (   65536)
//     cursor     [16384] i32                   @ 85065728   (   65536)
//     xq         [8192 x 1024] fp8             @ 85131264   ( 8388608)
//   (all aliased scratch consumed before GEMM1 writes out1)
// total: 150994944 bytes (144 MB)
// ---------------------------------------------------------------------------
extern "C" void kernel_launch(void* const* d_in, const int* in_sizes, int n_in,
                              void* d_out, int out_size, void* d_ws, size_t ws_size,
                              hipStream_t stream) {
  const float* hs     = (const float*)d_in[0];
  const float* weight = (const float*)d_in[1];   // [2,1024,4096]
  const float* root   = (const float*)d_in[2];   // [1024,4096]
  const float* bias   = (const float*)d_in[3];   // [4096]
  const float* wo     = (const float*)d_in[4];   // [4096,1024]
  const float* gamma  = (const float*)d_in[5];
  const float* beta   = (const float*)d_in[6];
  const int* edge_index = (const int*)d_in[7];   // [2,E]
  const int* edge_type  = (const int*)d_in[8];   // [E]
  float* out = (float*)d_out;

  char* ws = (char*)d_ws;
  u16*   hcat       = (u16*)(ws + 0);
  u16*   WcatT      = (u16*)(ws + 50331648);
  u16*   woT        = (u16*)(ws + 75497472);
  u16*   out1       = (u16*)(ws + 83886080);
  int*   bucket_src = (int*)(ws + 83886080);     // aliases out1 (consumed pre-GEMM1)
  int*   cnt        = (int*)(ws + 84934656);
  int*   off        = (int*)(ws + 85000192);
  int*   cursor     = (int*)(ws + 85065728);
  u32*   xq         = (u32*)(ws + 85131264);     // fp8 x, dense [8192][1024]

  (void)hipMemsetAsync(cnt, 0, 65536, stream);

  // LN + fused edge count
  ln_kernel<<<NNODE, 256, 0, stream>>>(hs, gamma, beta, hcat, xq,
                                       edge_index, edge_type, cnt);

  scan_kernel<<<1, 1024, 0, stream>>>(cnt, off, cursor);
  fill_kernel<<<E_NUM / 256, 256, 0, stream>>>(edge_index, edge_type, cursor, bucket_src);

  // fused: aggregate (L3 gather) + both weight transposes (HBM) overlap
  agg_cvt_kernel<<<AGG_BLOCKS + CVT1_BLOCKS + CVT2_BLOCKS, 256, 0, stream>>>(
      cnt, off, bucket_src, xq, hcat, weight, root, WcatT, wo, woT);

  // out1 = relu([h0|h1|x] @ [W0;W1;root] + bias)   [8192 x 4096] bf16
  gemm1_kernel<<<512, 512, 0, stream>>>(hcat, WcatT, bias, out1);

  // out = hs + out1 @ wo                            [8192 x 1024] f32
  gemm2_kernel<<<256, 512, 0, stream>>>(out1, woT, hs, out);
}

// Round 9
// 449.830 us; speedup vs baseline: 1.0745x; 1.0067x over previous
//
#include <hip/hip_runtime.h>

// ---------------------------------------------------------------------------
// T5GNNAdapt: LN -> RGCN scatter-mean (2 relations) -> [h0|h1|x] @ [W0;W1;root]
//             + bias -> relu -> @wo -> + residual
// Shapes: B=8,S=1024,D=1024,F=4096,E=262144,N=B*S=8192, K_cat=3072
// R7:  gemm1 -> 256^2 8-phase counted-vmcnt template.
// R8:  gemm2 -> same template (256x128, 2 phases/K-tile, VM2).
// R9:  FAILED gemm1 A-prefetch restructure (reverted). aggregate wave/bucket.
// R10: gemm1 LDS epilogue; count fused into ln.
// R11: lgkmcnt(0) drain removed + FENCE; gemm2 LDS epilogue. 459us.
// R12: agg+cvt fusion + readlane/pk-add aggregate. 452.8us (-6.4; below
//      falsifier -> aggregate/cvt were already small; gemm2 is the big
//      non-gemm1 item: 2-phase dbuf gives loads only ~320cyc to land).
// R13: gemm2 TRIPLE-buffered (A,B x3 = 144KB LDS), stage-2-ahead, VM6 per
//      K-tile: loads now age 3-4 phases (500+cyc) before the wait — same
//      pipeline depth principle as gemm1's 8-phase. Loop unrolled by 3
//      (tile t -> buf t%3, compile-time indices); tail tiles 60-63 peeled.
//      gemm1 and all other kernels untouched.
// ---------------------------------------------------------------------------

typedef unsigned short u16;
typedef unsigned int   u32;
typedef __attribute__((ext_vector_type(8))) short bf16x8;
typedef __attribute__((ext_vector_type(4))) float f32x4;
typedef __attribute__((ext_vector_type(2))) float f32x2;

#define E_NUM  262144
#define NNODE  8192
#define NBKT   (2 * NNODE)      // 16384 (rel,dst) buckets
#define DDIM   1024
#define FDIM   4096
#define KCAT   3072
#define LN_EPS 1e-6f

#define AGG_BLOCKS  (NBKT / 4)                     // 4096
#define CVT1_BLOCKS ((FDIM / 32) * (KCAT / 32))    // 12288
#define CVT2_BLOCKS ((DDIM / 32) * (FDIM / 32))    // 4096

struct alignas(8) u16x4 { u16 x, y, z, w; };

__device__ __forceinline__ u16 f2bf(float f) {
  u32 u = __float_as_uint(f);
  u32 r = u + 0x7fffu + ((u >> 16) & 1u);   // RNE
  return (u16)(r >> 16);
}
__device__ __forceinline__ float bf2f(u16 h) {
  return __uint_as_float(((u32)h) << 16);
}

// ---- fp8 e4m3fn (OCP) encode/decode; HW cvt when available ---------------
__device__ __forceinline__ u32 enc_fp8_1(float f) {
  u32 u = __float_as_uint(f);
  u32 s = u >> 31;
  u32 mag = u & 0x7fffffffu;
  mag = mag + 0x7ffffu + ((mag >> 20) & 1u);          // RNE to 3 mant bits
  if (mag > 0x43e00000u) mag = 0x43e00000u;           // clamp to 448
  u32 e = mag >> 23;
  return (e <= 120u) ? 0u
                     : ((s << 7) | ((e - 120u) << 3) | ((mag >> 20) & 7u));
}

__device__ __forceinline__ u32 pack4_fp8(float a, float b, float c, float d) {
#if __has_builtin(__builtin_amdgcn_cvt_pk_fp8_f32)
  int v = 0;
  v = __builtin_amdgcn_cvt_pk_fp8_f32(a, b, v, false);  // bytes 0,1
  v = __builtin_amdgcn_cvt_pk_fp8_f32(c, d, v, true);   // bytes 2,3
  return (u32)v;
#else
  return enc_fp8_1(a) | (enc_fp8_1(b) << 8) | (enc_fp8_1(c) << 16) |
         (enc_fp8_1(d) << 24);
#endif
}

__device__ __forceinline__ float dec_fp8_1(u32 b) {
  u32 e = (b >> 3) & 15u;
  u32 f = ((b & 0x80u) << 24) | ((e + 120u) << 23) | ((b & 7u) << 20);
  return e ? __uint_as_float(f) : 0.0f;
}

template <bool HI>
__device__ __forceinline__ f32x2 cvt2_fp8(u32 q) {
#if __has_builtin(__builtin_amdgcn_cvt_pk_f32_fp8)
  return __builtin_amdgcn_cvt_pk_f32_fp8((int)q, HI);   // HI is an immediate
#else
  f32x2 r;
  const u32 sh = HI ? 16u : 0u;
  r.x = dec_fp8_1((q >> sh) & 0xffu);
  r.y = dec_fp8_1((q >> (sh + 8)) & 0xffu);
  return r;
#endif
}

// accumulate one dwordx4 (16 fp8) into 8 f32x2 accumulators (pk adds)
__device__ __forceinline__ void acc16q(f32x2* ac, uint4 q) {
  ac[0] += cvt2_fp8<false>(q.x); ac[1] += cvt2_fp8<true>(q.x);
  ac[2] += cvt2_fp8<false>(q.y); ac[3] += cvt2_fp8<true>(q.y);
  ac[4] += cvt2_fp8<false>(q.z); ac[5] += cvt2_fp8<true>(q.z);
  ac[6] += cvt2_fp8<false>(q.w); ac[7] += cvt2_fp8<true>(q.w);
}

// 16-byte global -> LDS async copy (wave-uniform LDS base + lane*16 layout)
#define GLD16(gp, lp)                                              \
  __builtin_amdgcn_global_load_lds(                                \
      (__attribute__((address_space(1))) u32*)(gp),                \
      (__attribute__((address_space(3))) u32*)(lp), 16, 0, 0)

// ---------------------------------------------------------------------------
// K1: LayerNorm (one-pass) + fused edge-count. Writes bf16 x into
// hcat[:, 2048:3072] AND fp8 copy into dense xq[8192x1024]. Lanes 0-31 of
// each block also count 32 edges into cnt.
// ---------------------------------------------------------------------------
__global__ void ln_kernel(const float* __restrict__ hs,
                          const float* __restrict__ gamma,
                          const float* __restrict__ beta,
                          u16* __restrict__ hcat,
                          u32* __restrict__ xq,
                          const int* __restrict__ edge_index,
                          const int* __restrict__ edge_type,
                          int* __restrict__ cnt) {
  const int row = blockIdx.x;
  const int tid = threadIdx.x;
  const float4 v = ((const float4*)(hs + (size_t)row * DDIM))[tid];

  if (tid < 32) {                       // fused count: 32 edges per block
    const int e = (row << 5) + tid;
    const int d = edge_index[E_NUM + e];
    const int r = edge_type[e];
    atomicAdd(&cnt[r * NNODE + d], 1);
  }

  __shared__ float r1[256], r2[256];
  r1[tid] = v.x + v.y + v.z + v.w;
  r2[tid] = v.x * v.x + v.y * v.y + v.z * v.z + v.w * v.w;
  __syncthreads();
  for (int st = 128; st > 0; st >>= 1) {
    if (tid < st) { r1[tid] += r1[tid + st]; r2[tid] += r2[tid + st]; }
    __syncthreads();
  }
  const float mean = r1[0] * (1.0f / DDIM);
  const float var  = r2[0] * (1.0f / DDIM) - mean * mean;
  const float rs   = rsqrtf(var + LN_EPS);

  const int base = tid * 4;
  const float4 g = *(const float4*)(gamma + base);
  const float4 b = *(const float4*)(beta + base);
  const float o0 = (v.x - mean) * rs * g.x + b.x;
  const float o1 = (v.y - mean) * rs * g.y + b.y;
  const float o2 = (v.z - mean) * rs * g.z + b.z;
  const float o3 = (v.w - mean) * rs * g.w + b.w;
  u16x4 o;
  o.x = f2bf(o0); o.y = f2bf(o1); o.z = f2bf(o2); o.w = f2bf(o3);
  *(u16x4*)(hcat + (size_t)row * KCAT + 2048 + base) = o;
  xq[row * 256 + tid] = pack4_fp8(o0, o1, o2, o3);
}

// ---------------------------------------------------------------------------
// K3b: exclusive prefix sum over 16384 counts (single block, 1024 thr).
// ---------------------------------------------------------------------------
__global__ __launch_bounds__(1024) void scan_kernel(const int* __restrict__ cnt,
                                                    int* __restrict__ off,
                                                    int* __restrict__ cursor) {
  __shared__ int partial[1024];
  const int tid  = threadIdx.x;
  const int base = tid * 16;
  int local[16];
  int s = 0;
#pragma unroll
  for (int i = 0; i < 16; ++i) { local[i] = s; s += cnt[base + i]; }
  partial[tid] = s;
  __syncthreads();
  for (int st = 1; st < 1024; st <<= 1) {
    const int v = (tid >= st) ? partial[tid - st] : 0;
    __syncthreads();
    partial[tid] += v;
    __syncthreads();
  }
  const int pre = (tid == 0) ? 0 : partial[tid - 1];
#pragma unroll
  for (int i = 0; i < 16; ++i) {
    const int o = pre + local[i];
    off[base + i]    = o;
    cursor[base + i] = o;
  }
}

// ---------------------------------------------------------------------------
// K3c: scatter edge SOURCE ids into buckets (4B per edge, not row data).
// ---------------------------------------------------------------------------
__global__ void fill_kernel(const int* __restrict__ edge_index,
                            const int* __restrict__ edge_type,
                            int* __restrict__ cursor,
                            int* __restrict__ bucket_src) {
  const int e = blockIdx.x * 256 + threadIdx.x;
  const int s = edge_index[e];
  const int d = edge_index[E_NUM + e];
  const int r = edge_type[e];
  const int pos = atomicAdd(&cursor[r * NNODE + d], 1);
  bucket_src[pos] = s;
}

// ---------------------------------------------------------------------------
// K4: fused aggregate + weight transposes.
// Blocks [0, 4096): wave-per-bucket fp8 gather-mean (L3-bound).
//   readlane broadcast (SALU), 1-batch-ahead pipeline, f32x2 pk adds.
// Blocks [4096, 16384): WcatT transpose (HBM-bound — overlaps gather).
// Blocks [16384, 20480): woT transpose.
// ---------------------------------------------------------------------------
__device__ __forceinline__ void cvt_body(const float* __restrict__ srcA,
                                         const float* __restrict__ srcB,
                                         int splitK, int K, int N,
                                         u16* __restrict__ dst,
                                         int n0, int k0, int tx, int ty,
                                         float (*tile)[33]) {
  for (int i = ty; i < 32; i += 8) {
    const int k = k0 + i;
    const float v = (k < splitK) ? srcA[(size_t)k * N + n0 + tx]
                                 : srcB[(size_t)(k - splitK) * N + n0 + tx];
    tile[i][tx] = v;
  }
  __syncthreads();
  for (int i = ty; i < 32; i += 8) {
    dst[(size_t)(n0 + i) * K + k0 + tx] = f2bf(tile[tx][i]);
  }
}

__global__ __launch_bounds__(256) void agg_cvt_kernel(
    const int* __restrict__ cnt, const int* __restrict__ off,
    const int* __restrict__ bucket_src, const u32* __restrict__ xq,
    u16* __restrict__ hcat,
    const float* __restrict__ weight, const float* __restrict__ root,
    u16* __restrict__ WcatT,
    const float* __restrict__ wo, u16* __restrict__ woT) {
  __shared__ float tile[32][33];
  const int bx  = blockIdx.x;
  const int tid = threadIdx.x;

  if (bx >= AGG_BLOCKS) {
    const int tx = tid & 31, ty = tid >> 5;
    if (bx < AGG_BLOCKS + CVT1_BLOCKS) {
      const int idx = bx - AGG_BLOCKS;
      cvt_body(weight, root, 2048, KCAT, FDIM, WcatT,
               (idx & 127) * 32, (idx >> 7) * 32, tx, ty, tile);
    } else {
      const int idx = bx - AGG_BLOCKS - CVT1_BLOCKS;
      cvt_body(wo, wo, FDIM, FDIM, DDIM, woT,
               (idx & 31) * 32, (idx >> 5) * 32, tx, ty, tile);
    }
    return;
  }

  // ---- aggregate path ----
  const int b    = bx * 4 + (tid >> 6);   // bucket id
  const int lane = tid & 63;
  const int r    = b >> 13;
  const int node = b & (NNODE - 1);
  const int n     = cnt[b];
  const int start = off[b];

  f32x2 ac[8] = {};

#define LDROW(j) (*(const uint4*)(xq +                                     \
    (size_t)__builtin_amdgcn_readlane(myid, (j)) * 256 + lane * 4))

  for (int j0 = 0; j0 < n; j0 += 64) {
    const int m = min(n - j0, 64);
    const int myid = (lane < m) ? bucket_src[start + j0 + lane] : 0;
    const int nb = m & ~3;
    if (nb) {
      uint4 c0 = LDROW(0), c1 = LDROW(1), c2 = LDROW(2), c3 = LDROW(3);
      for (int j = 4; j < nb; j += 4) {
        const uint4 t0 = LDROW(j),     t1 = LDROW(j + 1);
        const uint4 t2 = LDROW(j + 2), t3 = LDROW(j + 3);
        acc16q(ac, c0); acc16q(ac, c1); acc16q(ac, c2); acc16q(ac, c3);
        c0 = t0; c1 = t1; c2 = t2; c3 = t3;
      }
      acc16q(ac, c0); acc16q(ac, c1); acc16q(ac, c2); acc16q(ac, c3);
    }
    for (int j = nb; j < m; ++j) {
      const uint4 x0 = LDROW(j);
      acc16q(ac, x0);
    }
  }
#undef LDROW

  const float inv = 1.0f / fmaxf((float)n, 1.0f);
  uint4 o0, o1;
  o0.x = (u32)f2bf(ac[0].x * inv) | ((u32)f2bf(ac[0].y * inv) << 16);
  o0.y = (u32)f2bf(ac[1].x * inv) | ((u32)f2bf(ac[1].y * inv) << 16);
  o0.z = (u32)f2bf(ac[2].x * inv) | ((u32)f2bf(ac[2].y * inv) << 16);
  o0.w = (u32)f2bf(ac[3].x * inv) | ((u32)f2bf(ac[3].y * inv) << 16);
  o1.x = (u32)f2bf(ac[4].x * inv) | ((u32)f2bf(ac[4].y * inv) << 16);
  o1.y = (u32)f2bf(ac[5].x * inv) | ((u32)f2bf(ac[5].y * inv) << 16);
  o1.z = (u32)f2bf(ac[6].x * inv) | ((u32)f2bf(ac[6].y * inv) << 16);
  o1.w = (u32)f2bf(ac[7].x * inv) | ((u32)f2bf(ac[7].y * inv) << 16);
  u16* dp = hcat + (size_t)node * KCAT + (size_t)r * DDIM + lane * 16;
  *(uint4*)(dp)     = o0;
  *(uint4*)(dp + 8) = o1;
}

// ---------------------------------------------------------------------------
// Shared 8-phase GEMM machinery (expanded in gemm kernels; names resolve to
// kernel-local variables at expansion site).
// R11: no forced lgkmcnt(0) — compiler inserts fine-grained lgkmcnt(N) per
// ds_read->MFMA dependency. FENCE (zero-cost asm memory clobber) after every
// s_barrier blocks cross-barrier load hoisting (cross-wave WAR guard).
// ---------------------------------------------------------------------------

#define MF16(a, b, c) __builtin_amdgcn_mfma_f32_16x16x32_bf16(a, b, c, 0, 0, 0)

#define FENCE asm volatile("" ::: "memory")

#define STAGE_A(t, p, b)                                                   \
  { GLD16(gA0 + (size_t)(t) * 64 + (size_t)(p) * KP,                       \
          &sA[b][(p) * 8192 + lofs0]);                                     \
    GLD16(gA1 + (size_t)(t) * 64 + (size_t)(p) * KP,                       \
          &sA[b][(p) * 8192 + lofs1]); }

#define STAGE_B(t, p, b)                                                   \
  { GLD16(gB0 + (size_t)(t) * 64 + (size_t)(p) * KP,                       \
          &sB[b][(p) * 8192 + lofs0]);                                     \
    GLD16(gB1 + (size_t)(t) * 64 + (size_t)(p) * KP,                       \
          &sB[b][(p) * 8192 + lofs1]); }

#define BVLOAD(b)                                                          \
  { const bf16x8* pB_ = (const bf16x8*)sB[b];                              \
    bv[0][0] = pB_[brow80 + sega0]; bv[0][1] = pB_[brow80 + sega1];        \
    bv[1][0] = pB_[brow81 + sega0]; bv[1][1] = pB_[brow81 + sega1];        \
    bv[2][0] = pB_[brow82 + sega0]; bv[2][1] = pB_[brow82 + sega1];        \
    bv[3][0] = pB_[brow83 + sega0]; bv[3][1] = pB_[brow83 + sega1]; }

#define NOWAIT ((void)0)
#define NOSTAGE ((void)0)
#define VM6 asm volatile("s_waitcnt vmcnt(6)" ::: "memory")
#define VM4 asm volatile("s_waitcnt vmcnt(4)" ::: "memory")
#define VM0 asm volatile("s_waitcnt vmcnt(0)" ::: "memory")

#define PHASE(Q, BUFI, STAGE, ENDW)                                        \
  { const bf16x8* pA_ = (const bf16x8*)sA[BUFI];                           \
    bf16x8 a00 = pA_[arow8[2 * (Q)] + sega0];                              \
    bf16x8 a01 = pA_[arow8[2 * (Q)] + sega1];                              \
    bf16x8 a10 = pA_[arow8[2 * (Q) + 1] + sega0];                          \
    bf16x8 a11 = pA_[arow8[2 * (Q) + 1] + sega1];                          \
    STAGE;                                                                 \
    __builtin_amdgcn_s_barrier();                                          \
    FENCE;                                                                 \
    __builtin_amdgcn_s_setprio(1);                                         \
    _Pragma("unroll")                                                      \
    for (int ni = 0; ni < 4; ++ni) {                                       \
      acc[2 * (Q)][ni]     = MF16(a00, bv[ni][0], acc[2 * (Q)][ni]);       \
      acc[2 * (Q)][ni]     = MF16(a01, bv[ni][1], acc[2 * (Q)][ni]);       \
      acc[2 * (Q) + 1][ni] = MF16(a10, bv[ni][0], acc[2 * (Q) + 1][ni]);   \
      acc[2 * (Q) + 1][ni] = MF16(a11, bv[ni][1], acc[2 * (Q) + 1][ni]);   \
    }                                                                      \
    __builtin_amdgcn_s_setprio(0);                                         \
    ENDW;                                                                  \
    __builtin_amdgcn_s_barrier();                                          \
    FENCE; }

// ---------------------------------------------------------------------------
// GEMM1: out1[8192x4096] = bf16(relu(hcat[8192x3072] @ WcatT^T + bias))
// 256x256 tile, BK=64, 512 thr / 8 waves (2Mx4N), 128 KiB dbuf LDS,
// 8-phase counted-vmcnt schedule; vmcnt(4) only at phases 4/8.
// Epilogue: bias+relu+f2bf -> LDS [128][264] u16 -> dwordx4 stores.
// ---------------------------------------------------------------------------
__global__ __launch_bounds__(512) void gemm1_kernel(
    const u16* __restrict__ A, const u16* __restrict__ Bt,
    const float* __restrict__ bias, u16* __restrict__ obf) {
  const int K = KCAT, N = FDIM;
  const int NT = K / 64;                    // 48 K-tiles
  const size_t KP = (size_t)128 * K;        // piece-1 global row offset
  __shared__ __align__(16) u16 smem[65536];   // 128 KB
  u16 (*sA)[16384] = (u16(*)[16384])(smem);          // 2 bufs x 256x64 bf16
  u16 (*sB)[16384] = (u16(*)[16384])(smem + 32768);  // 2 bufs x 256x64 bf16

  const int tid  = threadIdx.x;
  const int lane = tid & 63;
  const int wave = tid >> 6;
  const int wr = wave >> 2, wc = wave & 3;    // 2 x 4 wave grid
  const int lr = lane & 15, quad = lane >> 4;

  const int bid = blockIdx.x;
  const int swz = (bid & 7) * 64 + (bid >> 3);
  const int bm = (swz >> 4) * 256;
  const int bn = (swz & 15) * 256;

  int lofs0, lofs1;
  const u16 *gA0, *gA1, *gB0, *gB1;
  {
    const int s0 = tid,       r0 = s0 >> 3, g0 = (s0 & 7) ^ (r0 & 7);
    const int s1 = tid + 512, r1 = s1 >> 3, g1 = (s1 & 7) ^ (r1 & 7);
    gA0 = A  + (size_t)(bm + r0) * K + g0 * 8;
    gA1 = A  + (size_t)(bm + r1) * K + g1 * 8;
    gB0 = Bt + (size_t)(bn + r0) * K + g0 * 8;
    gB1 = Bt + (size_t)(bn + r1) * K + g1 * 8;
    lofs0 = s0 * 8; lofs1 = s1 * 8;
  }

  int arow8[8];
#pragma unroll
  for (int mi = 0; mi < 8; ++mi) arow8[mi] = (wr * 128 + mi * 16 + lr) * 8;
  const int brow80 = (wc * 64 +  0 + lr) * 8;
  const int brow81 = (wc * 64 + 16 + lr) * 8;
  const int brow82 = (wc * 64 + 32 + lr) * 8;
  const int brow83 = (wc * 64 + 48 + lr) * 8;
  const int sega0 = quad ^ (lr & 7);
  const int sega1 = (4 + quad) ^ (lr & 7);

  f32x4 acc[8][4] = {};
  bf16x8 bv[4][2];

  STAGE_B(0, 0, 0) STAGE_B(0, 1, 0)
  STAGE_A(0, 0, 0) STAGE_A(0, 1, 0)
  STAGE_B(1, 0, 1) STAGE_B(1, 1, 1)
  asm volatile("s_waitcnt vmcnt(4)" ::: "memory");
  __builtin_amdgcn_s_barrier();
  FENCE;

  for (int tt = 0; tt < NT - 2; tt += 2) {
    PHASE(0, 0, BVLOAD(0); STAGE_A(tt + 1, 0, 1), NOWAIT)
    PHASE(1, 0, STAGE_A(tt + 1, 1, 1), NOWAIT)
    PHASE(2, 0, STAGE_B(tt + 2, 0, 0), NOWAIT)
    PHASE(3, 0, STAGE_B(tt + 2, 1, 0), VM4)
    PHASE(0, 1, BVLOAD(1); STAGE_A(tt + 2, 0, 0), NOWAIT)
    PHASE(1, 1, STAGE_A(tt + 2, 1, 0), NOWAIT)
    PHASE(2, 1, STAGE_B(tt + 3, 0, 1), NOWAIT)
    PHASE(3, 1, STAGE_B(tt + 3, 1, 1), VM4)
  }
  PHASE(0, 0, BVLOAD(0); STAGE_A(NT - 1, 0, 1), NOWAIT)
  PHASE(1, 0, STAGE_A(NT - 1, 1, 1), NOWAIT)
  PHASE(2, 0, NOSTAGE, NOWAIT)
  PHASE(3, 0, NOSTAGE, VM0)
  PHASE(0, 1, BVLOAD(1), NOWAIT)
  PHASE(1, 1, NOSTAGE, NOWAIT)
  PHASE(2, 1, NOSTAGE, NOWAIT)
  PHASE(3, 1, NOSTAGE, NOWAIT)

  // --- epilogue: bias+relu+f2bf -> LDS [128][264] -> dwordx4 stores ---
  const int CPAD = 264;                       // 264*2B row pitch: 16B-aligned
#pragma unroll
  for (int h = 0; h < 2; ++h) {
    if (wr == h) {
#pragma unroll
      for (int mi = 0; mi < 8; ++mi) {
        const int lrow = mi * 16 + quad * 4;
#pragma unroll
        for (int ni = 0; ni < 4; ++ni) {
          const int col = wc * 64 + ni * 16 + lr;
          const float bb = bias[bn + col];
#pragma unroll
          for (int r = 0; r < 4; ++r) {
            const float v = acc[mi][ni][r] + bb;
            smem[(lrow + r) * CPAD + col] = f2bf(fmaxf(v, 0.0f));
          }
        }
      }
    }
    __syncthreads();
#pragma unroll
    for (int i = 0; i < 8; ++i) {
      const int chunk = tid + 512 * i;        // 4096 chunks of 16B
      const int row = chunk >> 5;             // 0..127
      const int seg = chunk & 31;             // 0..31
      const uint4 val = *(const uint4*)(smem + row * CPAD + seg * 8);
      *(uint4*)(obf + (size_t)(bm + h * 128 + row) * N + bn + seg * 8) = val;
    }
    __syncthreads();
  }
}

// ---------------------------------------------------------------------------
// GEMM2: out[8192x1024] = resid + out1[8192x4096] @ woT^T
// R13: 256x128 tile, BK=64, 512 thr / 8 waves (4Mx2N, 64x64/wave).
// TRIPLE-buffered LDS (3 x 48KB = 144KB): tile t -> buf t%3; during tile t
// stage tile t+2 into buf (t+2)%3 (always consumed, never live). VM6 at
// each K-tile end leaves exactly the newest tile's 6 loads in flight ->
// each load ages 3-4 phases (500+cyc) before its wait (was ~320cyc @ dbuf).
// Loop unrolled by 3 (compile-time buffer indices); tail 60-63 peeled.
// Epilogue: acc -> LDS f32 [128][132] -> float4 resid-add + store.
// ---------------------------------------------------------------------------
__global__ __launch_bounds__(512) void gemm2_kernel(
    const u16* __restrict__ A, const u16* __restrict__ Bt,
    const float* __restrict__ resid, float* __restrict__ out) {
  const int K = FDIM, N = DDIM;
  const int NT = K / 64;                    // 64 K-tiles
  const size_t KP = (size_t)128 * K;        // piece-1 global row offset
  __shared__ __align__(16) u16 smem[73728];   // 144 KB
  u16 (*sA)[16384] = (u16(*)[16384])(smem);           // 3 bufs x 256x64
  u16 (*sB)[8192]  = (u16(*)[8192])(smem + 49152);    // 3 bufs x 128x64

  const int tid  = threadIdx.x;
  const int lane = tid & 63;
  const int wave = tid >> 6;
  const int wr = wave >> 1, wc = wave & 1;    // 4 x 2 wave grid (64x64/wave)
  const int lr = lane & 15, quad = lane >> 4;

  const int bid = blockIdx.x;
  const int swz = (bid & 7) * 32 + (bid >> 3);
  const int bm = (swz >> 3) * 256;
  const int bn = (swz & 7) * 128;

  int lofs0, lofs1;
  const u16 *gA0, *gA1, *gB0, *gB1;
  {
    const int s0 = tid,       r0 = s0 >> 3, g0 = (s0 & 7) ^ (r0 & 7);
    const int s1 = tid + 512, r1 = s1 >> 3, g1 = (s1 & 7) ^ (r1 & 7);
    gA0 = A  + (size_t)(bm + r0) * K + g0 * 8;
    gA1 = A  + (size_t)(bm + r1) * K + g1 * 8;
    gB0 = Bt + (size_t)(bn + r0) * K + g0 * 8;   // B rows 0..63 (slot tid)
    gB1 = Bt + (size_t)(bn + r1) * K + g1 * 8;   // B rows 64..127 (tid+512)
    lofs0 = s0 * 8; lofs1 = s1 * 8;
  }

  int arow8[4];
#pragma unroll
  for (int mi = 0; mi < 4; ++mi) arow8[mi] = (wr * 64 + mi * 16 + lr) * 8;
  const int brow80 = (wc * 64 +  0 + lr) * 8;
  const int brow81 = (wc * 64 + 16 + lr) * 8;
  const int brow82 = (wc * 64 + 32 + lr) * 8;
  const int brow83 = (wc * 64 + 48 + lr) * 8;
  const int sega0 = quad ^ (lr & 7);
  const int sega1 = (4 + quad) ^ (lr & 7);

  f32x4 acc[4][4] = {};
  bf16x8 bv[4][2];

  // prologue: tiles 0 (buf0) and 1 (buf1), 6 loads each; VM6 -> tile0 landed.
  STAGE_B(0, 0, 0) STAGE_A(0, 0, 0) STAGE_A(0, 1, 0)
  STAGE_B(1, 0, 1) STAGE_A(1, 0, 1) STAGE_A(1, 1, 1)
  VM6;
  __builtin_amdgcn_s_barrier();
  FENCE;

  // main loop: tiles tt(b0), tt+1(b1), tt+2(b2); stage tt+2 -> b2,
  // tt+3 -> b0 (freed after tile tt), tt+4 -> b1 (freed after tt+1).
  for (int tt = 0; tt < NT - 4; tt += 3) {     // tt = 0,3,...,57
    PHASE(0, 0, BVLOAD(0); STAGE_A(tt + 2, 0, 2), NOWAIT)
    PHASE(1, 0, STAGE_A(tt + 2, 1, 2); STAGE_B(tt + 2, 0, 2), VM6)
    PHASE(0, 1, BVLOAD(1); STAGE_A(tt + 3, 0, 0), NOWAIT)
    PHASE(1, 1, STAGE_A(tt + 3, 1, 0); STAGE_B(tt + 3, 0, 0), VM6)
    PHASE(0, 2, BVLOAD(2); STAGE_A(tt + 4, 0, 1), NOWAIT)
    PHASE(1, 2, STAGE_A(tt + 4, 1, 1); STAGE_B(tt + 4, 0, 1), VM6)
  }
  // tail: tiles 60(b0), 61(b1), 62(b2), 63(b0); staged through 61.
  PHASE(0, 0, BVLOAD(0); STAGE_A(NT - 2, 0, 2), NOWAIT)
  PHASE(1, 0, STAGE_A(NT - 2, 1, 2); STAGE_B(NT - 2, 0, 2), VM6)
  PHASE(0, 1, BVLOAD(1); STAGE_A(NT - 1, 0, 0), NOWAIT)
  PHASE(1, 1, STAGE_A(NT - 1, 1, 0); STAGE_B(NT - 1, 0, 0), VM6)
  PHASE(0, 2, BVLOAD(2), NOWAIT)
  PHASE(1, 2, NOSTAGE, VM0)
  PHASE(0, 0, BVLOAD(0), NOWAIT)
  PHASE(1, 0, NOSTAGE, NOWAIT)

  // --- epilogue: acc -> LDS f32 [128][132] -> float4 resid+store ---
  float* smemf = (float*)smem;
  const int FPAD = 132;                     // 132*4B pitch: 16B-aligned
#pragma unroll
  for (int h = 0; h < 2; ++h) {
    __syncthreads();
    if ((wr >> 1) == h) {
#pragma unroll
      for (int mi = 0; mi < 4; ++mi) {
        const int srow0 = (wr & 1) * 64 + mi * 16 + quad * 4;
#pragma unroll
        for (int ni = 0; ni < 4; ++ni) {
          const int scol = wc * 64 + ni * 16 + lr;
#pragma unroll
          for (int r = 0; r < 4; ++r)
            smemf[(srow0 + r) * FPAD + scol] = acc[mi][ni][r];
        }
      }
    }
    __syncthreads();
#pragma unroll
    for (int i = 0; i < 8; ++i) {
      const int chunk = tid + 512 * i;        // 4096 chunks of 16B
      const int row = chunk >> 5;             // 0..127
      const int seg = chunk & 31;             // 0..31
      const float4 lv = *(const float4*)(smemf + row * FPAD + seg * 4);
      const size_t gofs = (size_t)(bm + h * 128 + row) * N + bn + seg * 4;
      const float4 rv = *(const float4*)(resid + gofs);
      float4 ov;
      ov.x = rv.x + lv.x; ov.y = rv.y + lv.y;
      ov.z = rv.z + lv.z; ov.w = rv.w + lv.w;
      *(float4*)(out + gofs) = ov;
    }
  }
}

// ---------------------------------------------------------------------------
// Workspace layout (bytes):
//   hcat       [8192 x 3072] bf16              @ 0          (50331648)
//   WcatT      [4096 x 3072] bf16              @ 50331648   (25165824)
//   woT        [1024 x 4096] bf16              @ 75497472   ( 8388608)
//   out1       [8192 x 4096] bf16              @ 83886080   (67108864)
//     bucket_src [262144] i32 (aliases out1)   @ 83886080   ( 1048576)
//     cnt        [16384] i32                   @ 84934656   (   65536)
//     off        [16384] i32                   @ 85000192   (   65536)
//     cursor     [16384] i32                   @ 85065728   (   65536)
//     xq         [8192 x 1024] fp8             @ 85131264   ( 8388608)
//   (all aliased scratch consumed before GEMM1 writes out1)
// total: 150994944 bytes (144 MB)
// ---------------------------------------------------------------------------
extern "C" void kernel_launch(void* const* d_in, const int* in_sizes, int n_in,
                              void* d_out, int out_size, void* d_ws, size_t ws_size,
                              hipStream_t stream) {
  const float* hs     = (const float*)d_in[0];
  const float* weight = (const float*)d_in[1];   // [2,1024,4096]
  const float* root   = (const float*)d_in[2];   // [1024,4096]
  const float* bias   = (const float*)d_in[3];   // [4096]
  const float* wo     = (const float*)d_in[4];   // [4096,1024]
  const float* gamma  = (const float*)d_in[5];
  const float* beta   = (const float*)d_in[6];
  const int* edge_index = (const int*)d_in[7];   // [2,E]
  const int* edge_type  = (const int*)d_in[8];   // [E]
  float* out = (float*)d_out;

  char* ws = (char*)d_ws;
  u16*   hcat       = (u16*)(ws + 0);
  u16*   WcatT      = (u16*)(ws + 50331648);
  u16*   woT        = (u16*)(ws + 75497472);
  u16*   out1       = (u16*)(ws + 83886080);
  int*   bucket_src = (int*)(ws + 83886080);     // aliases out1 (consumed pre-GEMM1)
  int*   cnt        = (int*)(ws + 84934656);
  int*   off        = (int*)(ws + 85000192);
  int*   cursor     = (int*)(ws + 85065728);
  u32*   xq         = (u32*)(ws + 85131264);     // fp8 x, dense [8192][1024]

  (void)hipMemsetAsync(cnt, 0, 65536, stream);

  // LN + fused edge count
  ln_kernel<<<NNODE, 256, 0, stream>>>(hs, gamma, beta, hcat, xq,
                                       edge_index, edge_type, cnt);

  scan_kernel<<<1, 1024, 0, stream>>>(cnt, off, cursor);
  fill_kernel<<<E_NUM / 256, 256, 0, stream>>>(edge_index, edge_type, cursor, bucket_src);

  // fused: aggregate (L3 gather) + both weight transposes (HBM) overlap
  agg_cvt_kernel<<<AGG_BLOCKS + CVT1_BLOCKS + CVT2_BLOCKS, 256, 0, stream>>>(
      cnt, off, bucket_src, xq, hcat, weight, root, WcatT, wo, woT);

  // out1 = relu([h0|h1|x] @ [W0;W1;root] + bias)   [8192 x 4096] bf16
  gemm1_kernel<<<512, 512, 0, stream>>>(hcat, WcatT, bias, out1);

  // out = hs + out1 @ wo                            [8192 x 1024] f32
  gemm2_kernel<<<256, 512, 0, stream>>>(out1, woT, hs, out);
}